// Round 7
// baseline (338.573 us; speedup 1.0000x reference)
//
#include <hip/hip_runtime.h>

// GAT 2-layer fused pipeline for MI355X.
// N=50000 nodes, E=800000 edges, H=4 heads, C=64 channels, D=4 att dims.
// Inputs bf16 (runtime-detected, fp32 fallback); edge_index int32.
//
// Round-21 = r20 (299 us) + SLICE-ORDERED GATHER for L2 locality.
//   r20 counters: aggr gathers have ~0% L2 hit (FETCH == zero-reuse bound;
//   every XCD reads the whole 12.8 MB x-table at random). Fix: partition
//   each node's edge list by src-slice (slice = src>>13; 8 slices x 2 MB of
//   x each, L2-resident per XCD). Scatter writes csr[dst][slice][16]; the
//   aggregation compacts its 16 nodes' sub-lists into LDS and walks slices
//   as the OUTER loop (4 nodes' accumulators live in regs) -> blocks
//   progress through slices roughly in phase -> gathers hit L2.
//   Same bytes, same edges, reassociated accumulation only.
//   Launches unchanged (memset, mega, aggr1+alpha2, aggr2).

#define N_NODES 50000
#define N_EDGES 800000
#define SLICES 8
#define SCAP 16       // per-(node,slice) capacity; lambda~2.6 -> P(ovfl)~1e-8
#define NCAP 64       // per-node total capacity (LDS list size)
#define NB_SC4 782    // ceil(N_EDGES/1024) scatter blocks (4 edges/thread)
#define NB_NODE1 782  // ceil(N_NODES/64) nodeA blocks
#define NB_SETUP 197  // 128 W1' + 64 W2' + 4 Bsd2 + 1 bias/flag

typedef __attribute__((ext_vector_type(8))) short short8;       // 8 bf16
typedef __attribute__((ext_vector_type(8))) _Float16 f16x8;     // 8 fp16
typedef __attribute__((ext_vector_type(4))) float f32x4;
typedef __attribute__((ext_vector_type(8))) unsigned short ushort8;
typedef __attribute__((ext_vector_type(4))) unsigned short us4v;

__device__ __forceinline__ float bf2f(unsigned short u){
  return __uint_as_float(((unsigned int)u) << 16);
}
__device__ __forceinline__ unsigned short f2bf(float f){
  unsigned int u = __float_as_uint(f);
  u = (u + 0x7FFFu + ((u >> 16) & 1u)) >> 16;   // round-to-nearest-even
  return (unsigned short)u;
}
__device__ __forceinline__ float ldf(const void* p, int i, bool bf){
  return bf ? bf2f(((const unsigned short*)p)[i]) : ((const float*)p)[i];
}

struct SetupPtrs {
  const void *W1, *A1, *aS1, *aD1, *b1, *W2, *A2, *aS2, *aD2, *b2, *x;
};

// ---------------- layer-1 alpha transform (per-block Bsd1 in LDS) ----------------

__device__ __forceinline__ void nodeA1_body(int nblk, int tid,
    const void* __restrict__ xin_, const void* __restrict__ A1,
    const void* __restrict__ aS1, const void* __restrict__ aD1,
    float* __restrict__ alpha_s, float* __restrict__ alpha_d)
{
  const int F = 128, STR = F + 8, KT = 4, CH = F / 8;
  __shared__ unsigned short xs[64 * 136];
  __shared__ unsigned short BsdL[2048];
  __shared__ int sbf;
  const int base = nblk * 64;
  if (tid < 64){                                  // per-block dtype probe
    unsigned int wv = ((const unsigned int*)xin_)[tid] & 0xFFFFu;
    unsigned int ex = (wv >> 7) & 0xFFu;
    bool hit = (ex >= 100u && ex <= 135u);
    unsigned long long mm = __ballot(hit);
    if (tid == 0) sbf = (__popcll(mm) > 40) ? 1 : 0;
  }
  __syncthreads();
  const bool bf = (sbf != 0);

  {                                               // local Bsd1 fragments (2048)
    const int lane = tid & 63, kt = tid >> 6, c = lane & 15;
    ushort8 v8;
    #pragma unroll
    for (int j = 0; j < 8; ++j){
      int k = kt * 32 + (lane >> 4) * 8 + j;
      float v = 0.f;
      if (c < 4){
        #pragma unroll
        for (int dd = 0; dd < 4; ++dd)
          v += ldf(A1, k * 16 + c * 4 + dd, bf) * ldf(aS1, c * 4 + dd, bf);
      } else if (c < 8){
        int hh = c - 4;
        #pragma unroll
        for (int dd = 0; dd < 4; ++dd)
          v += ldf(A1, k * 16 + hh * 4 + dd, bf) * ldf(aD1, hh * 4 + dd, bf);
      }
      v8[j] = f2bf(v);
    }
    *(ushort8*)&BsdL[tid * 8] = v8;
  }

  for (int v = tid; v < 64 * CH; v += 256){       // stage 64 x-rows
    int row = v / CH, c8 = v % CH;
    int node = base + row; if (node >= N_NODES) node = N_NODES - 1;
    size_t g = (size_t)node * F + c8 * 8;
    ushort8 u;
    if (bf){
      u = *(const ushort8*)((const unsigned short*)xin_ + g);
    } else {
      const float* xf = (const float*)xin_ + g;
      float4 f0 = *(const float4*)xf, f1 = *(const float4*)(xf + 4);
      u[0]=f2bf(f0.x); u[1]=f2bf(f0.y); u[2]=f2bf(f0.z); u[3]=f2bf(f0.w);
      u[4]=f2bf(f1.x); u[5]=f2bf(f1.y); u[6]=f2bf(f1.z); u[7]=f2bf(f1.w);
    }
    *(ushort8*)&xs[row * STR + c8 * 8] = u;
  }
  __syncthreads();

  const int wave = tid >> 6, l = tid & 63;
  const int quad = l >> 4, m = l & 15;
  const int wbase = base + wave * 16;

  f32x4 aacc = (f32x4)0.f;
  #pragma unroll
  for (int kt = 0; kt < KT; ++kt){
    short8 af = *(const short8*)&xs[(wave * 16 + m) * STR + kt * 32 + quad * 8];
    short8 sd = *(const short8*)&BsdL[((size_t)kt * 64 + l) * 8];
    aacc = __builtin_amdgcn_mfma_f32_16x16x32_bf16(af, sd, aacc, 0, 0, 0);
  }
  if (m < 8){
    float* dstp = (m < 4) ? alpha_s : alpha_d;
    int hh = m & 3;
    #pragma unroll
    for (int r = 0; r < 4; ++r){
      int node = wbase + quad * 4 + r;
      if (node < N_NODES) dstp[node * 4 + hh] = aacc[r];
    }
  }
}

// ---------------- mega kernel: slice-scatter || nodeA1 || weight-prep ----------------
// Blocks 0..781: scatter into csr[dst][slice][SCAP], slice = src>>13.
//   fill[dst*8+slice] doubles as the per-sub-list degree.
// Blocks 782..1563: nodeA1. Blocks 1564..1760: W1'/W2'/Bsd2/bias/flag.

__global__ __launch_bounds__(256) void k_mega(SetupPtrs S,
    const int* __restrict__ src, const int* __restrict__ dst,
    int* __restrict__ fill, unsigned short* __restrict__ csr,
    float* __restrict__ alpha_s, float* __restrict__ alpha_d,
    _Float16* __restrict__ Wb1f, _Float16* __restrict__ Wb2f,
    unsigned short* __restrict__ Bsd2f,
    float* __restrict__ bc1, float* __restrict__ bc2,
    int* __restrict__ flag)
{
  const int b = blockIdx.x, tid = threadIdx.x;
  if (b < NB_SC4){                                // slice scatter
    const int ebase = b * 1024 + tid;
    int d[4], s[4];
    #pragma unroll
    for (int i = 0; i < 4; ++i){
      int e = ebase + i * 256;
      bool ok = (e < N_EDGES);
      d[i] = ok ? dst[e] : -1;
      s[i] = ok ? src[e] : 0;
    }
    #pragma unroll
    for (int i = 0; i < 4; ++i){
      if (d[i] >= 0){
        unsigned sl = ((unsigned)s[i]) >> 13;     // 0..6
        unsigned bidx = (unsigned)d[i] * SLICES + sl;
        int r = atomicAdd(&fill[bidx], 1);
        if (r < SCAP) csr[(bidx << 4) + r] = (unsigned short)s[i];
      }
    }
    return;
  }
  if (b < NB_SC4 + NB_NODE1){                     // layer-1 alphas
    nodeA1_body(b - NB_SC4, tid, S.x, S.A1, S.aS1, S.aD1, alpha_s, alpha_d);
    return;
  }
  // weight-prep blocks (self-probed dtype)
  __shared__ int sbf;
  if (tid < 64){
    unsigned int w = ((const unsigned int*)S.x)[tid] & 0xFFFFu;
    unsigned int e = (w >> 7) & 0xFFu;
    bool hit = (e >= 100u && e <= 135u);
    unsigned long long m = __ballot(hit);
    if (tid == 0) sbf = (__popcll(m) > 40) ? 1 : 0;
  }
  __syncthreads();
  const bool bf = (sbf != 0);
  const int bw = b - NB_SC4 - NB_NODE1;           // 0..196
  if (bw < 128){                                  // W1' (K=512, KT=16)
    int t = bw * 256 + tid;
    int j = t & 7, lane = (t >> 3) & 63, kt = (t >> 9) & 15, nt = t >> 13;
    int q = kt * 32 + (lane >> 4) * 8 + j;
    int c = nt * 16 + (lane & 15);
    int h = q >> 7, f = q & 127;
    Wb1f[t] = (_Float16)(0.25f * ldf(S.W1, f * 256 + h * 64 + c, bf));
  } else if (bw < 192){                           // W2' (K=256, KT=8)
    int t = (bw - 128) * 256 + tid;
    int j = t & 7, lane = (t >> 3) & 63, kt = (t >> 9) & 7, nt = t >> 12;
    int q = kt * 32 + (lane >> 4) * 8 + j;
    int c = nt * 16 + (lane & 15);
    int h = q >> 6, f = q & 63;
    Wb2f[t] = (_Float16)(0.25f * ldf(S.W2, f * 256 + h * 64 + c, bf));
  } else if (bw < 196){                           // Bsd2 fragments
    int t = (bw - 192) * 256 + tid;
    int j = t & 7, lane = (t >> 3) & 63, kt = t >> 9;
    int k = kt * 32 + (lane >> 4) * 8 + j;
    int c = lane & 15;
    float v = 0.f;
    if (c < 4){
      for (int dd = 0; dd < 4; ++dd)
        v += ldf(S.A2, k * 16 + c * 4 + dd, bf) * ldf(S.aS2, c * 4 + dd, bf);
    } else if (c < 8){
      int h = c - 4;
      for (int dd = 0; dd < 4; ++dd)
        v += ldf(S.A2, k * 16 + h * 4 + dd, bf) * ldf(S.aD2, h * 4 + dd, bf);
    }
    Bsd2f[t] = f2bf(v);
  } else {                                        // bias copies + flag
    if (tid < 64)       bc1[tid] = ldf(S.b1, tid, bf);
    else if (tid < 128) bc2[tid - 64] = ldf(S.b2, tid - 64, bf);
    else if (tid == 128) *flag = bf ? 1 : 0;
  }
}

// ---------------- aggregation: LDS-compacted slice-ordered gather + MFMA ----------------
// Pre-phase: compact the block's 16 nodes' (slice-major) sub-lists into LDS
//   els[16][64] with per-node slice prefix sst[16][9].
// Phase 1: slice-OUTER loop; 4 nodes per wave accumulate in registers; gathers
//   within slice sl touch only a 2MB (1MB for layer 2) window -> L2 hits.
// Phase 2: wave w computes out cols nt=w of [16]x[K=4*FIN]@W'[K,64], +bias,
//   leaky 0.1. MODE 0: also x2t stash + fused layer-2 alpha (Bsd2 MFMA).

template<int FIN, bool BF>
__device__ __forceinline__ void ldrow(const void* xg, unsigned s, int f0,
                                      float (&out)[FIN / 16])
{
  const int NFL = FIN / 16;
  if (BF){
    const unsigned short* p = (const unsigned short*)xg + (size_t)s * FIN + f0;
    if (NFL == 8){
      ushort8 u = *(const ushort8*)p;
      #pragma unroll
      for (int j = 0; j < NFL; ++j) out[j] = bf2f(u[j]);
    } else {
      us4v u = *(const us4v*)p;
      #pragma unroll
      for (int j = 0; j < NFL; ++j) out[j] = bf2f(u[j]);
    }
  } else {
    const float* p = (const float*)xg + (size_t)s * FIN + f0;
    #pragma unroll
    for (int j = 0; j < NFL; ++j) out[j] = p[j];
  }
}

template<int FIN, bool BF, int STR>
__device__ __forceinline__ void aggr_phase1(const void* __restrict__ xg,
    const float* __restrict__ alpha_s, const float* __restrict__ alpha_d,
    const unsigned short (*__restrict__ els)[NCAP], const int (*__restrict__ sst)[SLICES + 1],
    _Float16* __restrict__ ylds, int base, int w, int l)
{
  const int NFL = FIN / 16;
  const int h = l >> 4, sub = l & 15, f0 = sub * NFL;
  const int j0 = w * 4;

  float den[4] = {0.f, 0.f, 0.f, 0.f};
  float acc[4][NFL];
  #pragma unroll
  for (int r = 0; r < 4; ++r)
    #pragma unroll
    for (int j = 0; j < NFL; ++j) acc[r][j] = 0.f;
  float adv[4];
  #pragma unroll
  for (int r = 0; r < 4; ++r) adv[r] = alpha_d[(base + j0 + r) * 4 + h];

  for (int sl = 0; sl < SLICES; ++sl){            // slice-outer: L2 window
    #pragma unroll
    for (int r = 0; r < 4; ++r){
      const unsigned short* cp = els[j0 + r];
      int p  = sst[j0 + r][sl];
      int en = sst[j0 + r][sl + 1];
      for (; p + 4 <= en; p += 4){                // 4-edge batch (LDS scalar reads)
        unsigned sx = cp[p], sy = cp[p+1], sz = cp[p+2], sw = cp[p+3];
        float ax = alpha_s[sx * 4 + h];
        float ay = alpha_s[sy * 4 + h];
        float az = alpha_s[sz * 4 + h];
        float aw = alpha_s[sw * 4 + h];
        float vx[NFL], vy[NFL], vz[NFL], vw[NFL];
        ldrow<FIN, BF>(xg, sx, f0, vx);
        ldrow<FIN, BF>(xg, sy, f0, vy);
        ldrow<FIN, BF>(xg, sz, f0, vz);
        ldrow<FIN, BF>(xg, sw, f0, vw);
        float e0 = ax + adv[r]; e0 = fmaxf(e0, 0.2f * e0); float w0 = __expf(e0);
        float e1 = ay + adv[r]; e1 = fmaxf(e1, 0.2f * e1); float w1 = __expf(e1);
        float e2 = az + adv[r]; e2 = fmaxf(e2, 0.2f * e2); float w2 = __expf(e2);
        float e3 = aw + adv[r]; e3 = fmaxf(e3, 0.2f * e3); float w3 = __expf(e3);
        den[r] += w0; den[r] += w1; den[r] += w2; den[r] += w3;
        #pragma unroll
        for (int j = 0; j < NFL; ++j)
          acc[r][j] += w0 * vx[j] + w1 * vy[j] + w2 * vz[j] + w3 * vw[j];
      }
      for (; p < en; ++p){                        // tail
        unsigned s = cp[p];
        float a = alpha_s[s * 4 + h];
        float v0[NFL];
        ldrow<FIN, BF>(xg, s, f0, v0);
        float e = a + adv[r]; e = fmaxf(e, 0.2f * e); float wgt = __expf(e);
        den[r] += wgt;
        #pragma unroll
        for (int j = 0; j < NFL; ++j) acc[r][j] += wgt * v0[j];
      }
    }
  }
  #pragma unroll
  for (int r = 0; r < 4; ++r){
    const float rh = (den[r] > 0.f) ? (1.f / den[r]) : 0.f;
    _Float16* yp = &ylds[(j0 + r) * STR + h * FIN + f0];
    #pragma unroll
    for (int j = 0; j < NFL; ++j) yp[j] = (_Float16)(acc[r][j] * rh);
  }
}

template<int FIN, int MODE>
__global__ __launch_bounds__(256) void k_aggrX(
    const void* __restrict__ xg,                 // [N, FIN] bf16 (or fp32 if MODE 0 && !flag)
    const float* __restrict__ alpha_s, const float* __restrict__ alpha_d,
    const int* __restrict__ fill, const unsigned short* __restrict__ csr,
    const _Float16* __restrict__ Wf,             // f16 B-frags, NT=4, KT=FIN/8
    const float* __restrict__ bias, void* __restrict__ out,
    const int* __restrict__ flag,
    const unsigned short* __restrict__ Bsd2f,    // MODE 0 only
    float* __restrict__ as2, float* __restrict__ ad2)
{
  const int K = 4 * FIN, KT = K / 32, STR = K + 8;
  __shared__ _Float16 ylds[16 * (4 * FIN + 8)];
  __shared__ unsigned short x2t[16 * 72];         // MODE 0: 16-node x2 bf16 tile
  __shared__ unsigned short els[16][NCAP];        // compacted slice-major edge lists
  __shared__ int sst[16][SLICES + 1];             // per-node slice prefix
  __shared__ int cs_[16][SLICES];
  const int tid = threadIdx.x, w = tid >> 6, l = tid & 63;
  const int base = blockIdx.x * 16;               // N divisible by 16

  // ---- compaction pre-phase ----
  if (tid < 128){
    int j = tid >> 3, sl = tid & 7;
    int c = fill[(base + j) * SLICES + sl];
    cs_[j][sl] = (c > SCAP) ? SCAP : c;
  }
  __syncthreads();
  if (tid < 16){
    int s0 = 0;
    sst[tid][0] = 0;
    #pragma unroll
    for (int sl = 0; sl < SLICES; ++sl){
      int c = cs_[tid][sl];
      if (s0 + c > NCAP) c = NCAP - s0;
      s0 += c;
      sst[tid][sl + 1] = s0;
    }
  }
  __syncthreads();
  if (tid < 128){
    int j = tid >> 3, sl = tid & 7;
    int st = sst[j][sl], c = sst[j][sl + 1] - st;
    const unsigned short* gp = csr + ((((unsigned)(base + j)) * SLICES + sl) << 4);
    ushort8 v0 = *(const ushort8*)gp;             // 32B-aligned region
    ushort8 v1 = *(const ushort8*)(gp + 8);
    #pragma unroll
    for (int q = 0; q < 16; ++q){
      unsigned short vq = (q < 8) ? v0[q] : v1[q - 8];
      if (q < c) els[j][st + q] = vq;
    }
  }
  __syncthreads();

  // ---- phase 1: slice-ordered aggregation ----
  if (MODE == 0 && *flag == 0)
    aggr_phase1<FIN, false, STR>(xg, alpha_s, alpha_d, els, sst, ylds, base, w, l);
  else
    aggr_phase1<FIN, true,  STR>(xg, alpha_s, alpha_d, els, sst, ylds, base, w, l);
  __syncthreads();

  // ---- phase 2: stacked-W MFMA epilogue ----
  const int quad = l >> 4, m = l & 15;
  const int nt = w;
  f32x4 cacc = (f32x4)0.f;
  #pragma unroll
  for (int kt = 0; kt < KT; ++kt){
    f16x8 av = *(const f16x8*)&ylds[m * STR + kt * 32 + quad * 8];
    f16x8 bv = *(const f16x8*)(Wf + ((size_t)(nt * KT + kt) * 64 + l) * 8);
    cacc = __builtin_amdgcn_mfma_f32_16x16x32_f16(av, bv, cacc, 0, 0, 0);
  }
  const int c = nt * 16 + m;
  const float bs = bias[c];
  #pragma unroll
  for (int r2 = 0; r2 < 4; ++r2){
    int node = base + quad * 4 + r2;
    float v = cacc[r2] + bs;
    v = fmaxf(v, 0.1f * v);                       // post-layer leaky 0.1
    if (MODE == 0){
      unsigned short o = f2bf(v);
      ((unsigned short*)out)[(size_t)node * 64 + c] = o;
      x2t[(quad * 4 + r2) * 72 + c] = o;          // stash for fused alpha2
    } else {
      if (*flag) ((unsigned short*)out)[(size_t)node * 64 + c] = f2bf(v);
      else       ((float*)out)[(size_t)node * 64 + c] = v;
    }
  }

  if (MODE == 0){                                 // fused layer-2 alpha (1 wave)
    __syncthreads();
    if (w == 0){
      f32x4 aacc = (f32x4)0.f;
      #pragma unroll
      for (int kt = 0; kt < 2; ++kt){
        short8 af = *(const short8*)&x2t[m * 72 + kt * 32 + quad * 8];
        short8 sd = *(const short8*)(Bsd2f + ((size_t)kt * 64 + l) * 8);
        aacc = __builtin_amdgcn_mfma_f32_16x16x32_bf16(af, sd, aacc, 0, 0, 0);
      }
      if (m < 8){
        float* dstp = (m < 4) ? as2 : ad2;
        int hh = m & 3;
        #pragma unroll
        for (int r = 0; r < 4; ++r){
          int node = base + quad * 4 + r;
          dstp[node * 4 + hh] = aacc[r];
        }
      }
    }
  }
}

// ---------------- launch ----------------

extern "C" void kernel_launch(void* const* d_in, const int* in_sizes, int n_in,
                              void* d_out, int out_size, void* d_ws, size_t ws_size,
                              hipStream_t stream)
{
  const void* x  = d_in[0];
  const int* ei  = (const int*)d_in[1];
  const int* src = ei;
  const int* dst = ei + N_EDGES;

  char* ws = (char*)d_ws;                      // footprint ~24.2 MB
  unsigned short* csr = (unsigned short*)(ws);             // [N][8][16] ushort (12.8 MB)
  unsigned short* x2  = (unsigned short*)(ws + 12800000);  // [N,64] bf16 (6.4 MB)
  float* as_    = (float*)(ws + 19200000);     // [N,4] layer-1 alpha_src
  float* ad_    = (float*)(ws + 20000000);     // [N,4] layer-1 alpha_dst
  float* as2_   = (float*)(ws + 20800000);     // [N,4] layer-2 alpha_src
  float* ad2_   = (float*)(ws + 21600000);     // [N,4] layer-2 alpha_dst
  int*   fill   = (int*)  (ws + 22400000);     // [N*8] sub-list counters (1.6 MB)
  _Float16* Wb1f = (_Float16*)(ws + 24000000); // [32768] f16 stacked-W1 frags
  _Float16* Wb2f = (_Float16*)(ws + 24065536); // [16384] f16 stacked-W2 frags
  unsigned short* Bsd2f = (unsigned short*)(ws + 24098304);  // [1024] bf16
  float* bc1    = (float*)(ws + 24100352);     // [64]
  float* bc2    = (float*)(ws + 24100608);     // [64]
  int*   flag   = (int*)  (ws + 24100864);     // dtype flag (1 = bf16)

  hipMemsetAsync(fill, 0, N_NODES * SLICES * sizeof(int), stream);

  SetupPtrs S;
  S.W1 = d_in[2];  S.A1 = d_in[3];  S.aS1 = d_in[4];  S.aD1 = d_in[5];  S.b1 = d_in[6];
  S.W2 = d_in[7];  S.A2 = d_in[8];  S.aS2 = d_in[9];  S.aD2 = d_in[10]; S.b2 = d_in[11];
  S.x  = x;

  // slice-scatter (782) || layer-1 alphas (782) || weight-prep (197)
  k_mega<<<NB_SC4 + NB_NODE1 + NB_SETUP, 256, 0, stream>>>(
      S, src, dst, fill, csr, as_, ad_, Wb1f, Wb2f, Bsd2f, bc1, bc2, flag);

  // layer 1: slice-ordered aggregation + stacked-W1 MFMA -> x2 bf16; + fused alpha2
  k_aggrX<128, 0><<<N_NODES / 16, 256, 0, stream>>>(
      x, as_, ad_, fill, csr, Wb1f, bc1, x2, flag, Bsd2f, as2_, ad2_);

  // layer 2: slice-ordered aggregation + stacked-W2 MFMA -> final out
  k_aggrX<64, 1><<<N_NODES / 16, 256, 0, stream>>>(
      x2, as2_, ad2_, fill, csr, Wb2f, bc2, d_out, flag, Bsd2f, as2_, ad2_);
}

// Round 8
// 295.547 us; speedup vs baseline: 1.1456x; 1.1456x over previous
//
#include <hip/hip_runtime.h>

// GAT 2-layer fused pipeline for MI355X.
// N=50000 nodes, E=800000 edges, H=4 heads, C=64 channels, D=4 att dims.
// Inputs bf16 (runtime-detected, fp32 fallback); edge_index int32.
//
// Round-22 = r19 (proven 291.5 us; r20 fusion +8, r21 slice-order +47 both
// reverted) + ONE change: fill counters padded to one per 64B cache line
// (stride-16 int). r20 counters showed the scatter at VALUBusy 2%, 0.65 TB/s
// -> atomic-latency bound; dense fill = 256 atomics/line serializing at the
// TCC atomic unit. Padding cuts line collisions 16x. Everything else is
// byte-identical to r19 (absmax 1.2207e-4).
//
// Structure (r16-r19): AGGREGATE-THEN-TRANSFORM.
//   sum_e w*(x_src@W) = (sum_e w*x_src)@W; per dst aggregate softmax-weighted
//   input features per head (head = l>>4, lane owns FIN/16 features, ONE exp
//   chain per edge, 8-edge batches), then stacked-weight MFMA epilogue
//   W'[h*Fin+f, c] = 0.25*W[f, h*64+c] (head-mean folded). No hmat.

#define N_NODES 50000
#define N_EDGES 800000
#define CAP 64        // padded-CSR per-node capacity (max degree ~40 here)
#define FILLSTR 16    // fill counter stride in ints (one counter per 64B line)
#define NB_SC4 782    // ceil(N_EDGES/1024) scatter blocks (4 edges/thread)
#define NB_NODE1 782  // ceil(N_NODES/64) nodeA blocks

typedef __attribute__((ext_vector_type(8))) short short8;       // 8 bf16
typedef __attribute__((ext_vector_type(8))) _Float16 f16x8;     // 8 fp16
typedef __attribute__((ext_vector_type(4))) float f32x4;
typedef __attribute__((ext_vector_type(8))) unsigned short ushort8;
typedef __attribute__((ext_vector_type(4))) unsigned short us4v;

__device__ __forceinline__ float bf2f(unsigned short u){
  return __uint_as_float(((unsigned int)u) << 16);
}
__device__ __forceinline__ unsigned short f2bf(float f){
  unsigned int u = __float_as_uint(f);
  u = (u + 0x7FFFu + ((u >> 16) & 1u)) >> 16;   // round-to-nearest-even
  return (unsigned short)u;
}
__device__ __forceinline__ float ldf(const void* p, int i, bool bf){
  return bf ? bf2f(((const unsigned short*)p)[i]) : ((const float*)p)[i];
}

// ---------------- weight prep (205 blocks) + dtype flag ----------------
// Blocks 0..127: W1' stacked-f16 frags; 128..191: W2'; 192..199: Bsd1 (bf16);
// 200..203: Bsd2; 204: bias copies + flag. Dtype self-detected per block.
// Stacked weight: W'[q, c] = 0.25*W[f, h*64+c], q = h*Fin+f  (head-mean folded).
// B-frag layout (mfma 16x16x32): Wf[((nt*KT+kt)*64+lane)*8+j] =
//   W'[q = kt*32+(lane>>4)*8+j][c = nt*16+(lane&15)], NT=4.
struct SetupPtrs {
  const void *W1, *A1, *aS1, *aD1, *b1, *W2, *A2, *aS2, *aD2, *b2, *x;
};

__global__ __launch_bounds__(256) void k_setup(SetupPtrs S,
    _Float16* __restrict__ Wb1f, _Float16* __restrict__ Wb2f,
    unsigned short* __restrict__ Bsd1f, unsigned short* __restrict__ Bsd2f,
    float* __restrict__ bc1, float* __restrict__ bc2,
    int* __restrict__ flag)
{
  __shared__ int sbf;
  const int tid = threadIdx.x;
  if (tid < 64){                                  // wave 0: dtype probe
    unsigned int w = ((const unsigned int*)S.x)[tid] & 0xFFFFu;
    unsigned int e = (w >> 7) & 0xFFu;
    bool hit = (e >= 100u && e <= 135u);
    unsigned long long m = __ballot(hit);
    if (tid == 0) sbf = (__popcll(m) > 40) ? 1 : 0;
  }
  __syncthreads();
  const bool bf = (sbf != 0);
  const int bw = blockIdx.x;
  if (bw < 128){                                  // W1' (K=512, KT=16): 32768 elems
    int t = bw * 256 + tid;
    int j = t & 7, lane = (t >> 3) & 63, kt = (t >> 9) & 15, nt = t >> 13;
    int q = kt * 32 + (lane >> 4) * 8 + j;        // 0..511
    int c = nt * 16 + (lane & 15);
    int h = q >> 7, f = q & 127;
    Wb1f[t] = (_Float16)(0.25f * ldf(S.W1, f * 256 + h * 64 + c, bf));
  } else if (bw < 192){                           // W2' (K=256, KT=8): 16384 elems
    int t = (bw - 128) * 256 + tid;
    int j = t & 7, lane = (t >> 3) & 63, kt = (t >> 9) & 7, nt = t >> 12;
    int q = kt * 32 + (lane >> 4) * 8 + j;        // 0..255
    int c = nt * 16 + (lane & 15);
    int h = q >> 6, f = q & 63;
    Wb2f[t] = (_Float16)(0.25f * ldf(S.W2, f * 256 + h * 64 + c, bf));
  } else if (bw < 200){                           // Bsd1 fragments: 2048 elems (kt<4)
    int t = (bw - 192) * 256 + tid;
    int j = t & 7, lane = (t >> 3) & 63, kt = t >> 9;
    int k = kt * 32 + (lane >> 4) * 8 + j;
    int c = lane & 15;
    float v = 0.f;
    if (c < 4){
      for (int dd = 0; dd < 4; ++dd)
        v += ldf(S.A1, k * 16 + c * 4 + dd, bf) * ldf(S.aS1, c * 4 + dd, bf);
    } else if (c < 8){
      int h = c - 4;
      for (int dd = 0; dd < 4; ++dd)
        v += ldf(S.A1, k * 16 + h * 4 + dd, bf) * ldf(S.aD1, h * 4 + dd, bf);
    }
    Bsd1f[t] = f2bf(v);
  } else if (bw < 204){                           // Bsd2 fragments: 1024 elems (kt<2)
    int t = (bw - 200) * 256 + tid;
    int j = t & 7, lane = (t >> 3) & 63, kt = t >> 9;
    int k = kt * 32 + (lane >> 4) * 8 + j;
    int c = lane & 15;
    float v = 0.f;
    if (c < 4){
      for (int dd = 0; dd < 4; ++dd)
        v += ldf(S.A2, k * 16 + c * 4 + dd, bf) * ldf(S.aS2, c * 4 + dd, bf);
    } else if (c < 8){
      int h = c - 4;
      for (int dd = 0; dd < 4; ++dd)
        v += ldf(S.A2, k * 16 + h * 4 + dd, bf) * ldf(S.aD2, h * 4 + dd, bf);
    }
    Bsd2f[t] = f2bf(v);
  } else {                                        // bias copies + flag
    if (tid < 64)       bc1[tid] = ldf(S.b1, tid, bf);
    else if (tid < 128) bc2[tid - 64] = ldf(S.b2, tid - 64, bf);
    else if (tid == 128) *flag = bf ? 1 : 0;
  }
}

// ---------------- alpha transform ----------------

template<int F, bool DYN>
__device__ __forceinline__ void nodeA_body(int nblk, int tid,
    const void* __restrict__ xin_, const unsigned short* __restrict__ Bsdf,
    float* __restrict__ alpha_s, float* __restrict__ alpha_d,
    const int* __restrict__ flag)
{
  const int STR = F + 8;                   // row stride in ushorts (16B pad)
  const int KT  = F / 32;
  const int CH  = F / 8;
  __shared__ unsigned short xs[64 * (F + 8)];
  const int base = nblk * 64;
  bool bf = true;
  if (DYN) bf = (*flag != 0);
  for (int v = tid; v < 64 * CH; v += 256){
    int row = v / CH, c8 = v % CH;
    int node = base + row; if (node >= N_NODES) node = N_NODES - 1;
    size_t g = (size_t)node * F + c8 * 8;
    ushort8 u;
    if (!DYN || bf){
      u = *(const ushort8*)((const unsigned short*)xin_ + g);
    } else {
      const float* xf = (const float*)xin_ + g;
      float4 f0 = *(const float4*)xf, f1 = *(const float4*)(xf + 4);
      u[0]=f2bf(f0.x); u[1]=f2bf(f0.y); u[2]=f2bf(f0.z); u[3]=f2bf(f0.w);
      u[4]=f2bf(f1.x); u[5]=f2bf(f1.y); u[6]=f2bf(f1.z); u[7]=f2bf(f1.w);
    }
    *(ushort8*)&xs[row * STR + c8 * 8] = u;
  }
  __syncthreads();

  const int wave = tid >> 6, l = tid & 63;
  const int quad = l >> 4, m = l & 15;
  const int wbase = base + wave * 16;

  f32x4 aacc = (f32x4)0.f;
  #pragma unroll
  for (int kt = 0; kt < KT; ++kt){
    short8 af = *(const short8*)&xs[(wave * 16 + m) * STR + kt * 32 + quad * 8];
    short8 sdfrag = *(const short8*)(Bsdf + ((size_t)kt * 64 + l) * 8);
    aacc = __builtin_amdgcn_mfma_f32_16x16x32_bf16(af, sdfrag, aacc, 0, 0, 0);
  }
  if (m < 8){
    float* dstp = (m < 4) ? alpha_s : alpha_d;
    int hh = m & 3;
    #pragma unroll
    for (int r = 0; r < 4; ++r){
      int node = wbase + quad * 4 + r;
      if (node < N_NODES) dstp[node * 4 + hh] = aacc[r];
    }
  }
}

// ---------------- fused padded-CSR scatter (ushort, 4-edge ILP) + layer-1 alpha ----------------
// Blocks 0..781: scatter; fill[dst*FILLSTR] (one counter per 64B line).
// Blocks 782..1563: nodeA1 (independent, overlaps scatter latency).

__global__ __launch_bounds__(256) void k_scatter_nodeA1(
    const int* __restrict__ src, const int* __restrict__ dst,
    int* __restrict__ fill, unsigned short* __restrict__ csr,
    const void* __restrict__ xin_, const unsigned short* __restrict__ Bsdf,
    float* __restrict__ alpha_s, float* __restrict__ alpha_d,
    const int* __restrict__ flag)
{
  const int b = blockIdx.x, tid = threadIdx.x;
  if (b < NB_SC4){
    const int ebase = b * 1024 + tid;
    int d[4], s[4];
    #pragma unroll
    for (int i = 0; i < 4; ++i){
      int e = ebase + i * 256;
      bool ok = (e < N_EDGES);
      d[i] = ok ? dst[e] : -1;
      s[i] = ok ? src[e] : 0;
    }
    #pragma unroll
    for (int i = 0; i < 4; ++i){
      if (d[i] >= 0){
        int r = atomicAdd(&fill[(unsigned)d[i] * FILLSTR], 1);
        if (r < CAP) csr[((unsigned)d[i] << 6) + r] = (unsigned short)s[i];
      }
    }
    return;
  }
  nodeA_body<128, true>(b - NB_SC4, tid, xin_, Bsdf, alpha_s, alpha_d, flag);
}

// standalone layer-2 alpha kernel (x2 is always bf16)
template<int F, bool DYN>
__global__ __launch_bounds__(256) void k_nodeA(const void* __restrict__ xin_,
    const unsigned short* __restrict__ Bsdf,
    float* __restrict__ alpha_s, float* __restrict__ alpha_d,
    const int* __restrict__ flag)
{
  nodeA_body<F, DYN>(blockIdx.x, threadIdx.x, xin_, Bsdf, alpha_s, alpha_d, flag);
}

// ---------------- weighted-feature aggregation + stacked-W MFMA epilogue ----------------
// Block = 256 thr = 4 waves, 16 dst nodes (wave w owns nodes base+4w..base+4w+3).
// Phase 1: h = l>>4, sub = l&15; lane owns NFL = FIN/16 features, ONE exp chain
//   per edge, 8-edge batches. y -> fp16 LDS tile [16][4*FIN].
// Phase 2: wave w computes output n-tile nt=w of [16 nodes]x[K=4*FIN]@W'[K,64]
//   via KT f16 MFMAs; + bias, leaky 0.1, store.
// MODE 0: layer 1 — x gather dtype per flag; out x2 bf16.
// MODE 1: layer 2 — x2 always bf16; out per flag (bf16 else fp32).

template<int FIN, bool BF>
__device__ __forceinline__ void ldrow(const void* xg, unsigned s, int f0,
                                      float (&out)[FIN / 16])
{
  const int NFL = FIN / 16;
  if (BF){
    const unsigned short* p = (const unsigned short*)xg + (size_t)s * FIN + f0;
    if (NFL == 8){
      ushort8 u = *(const ushort8*)p;
      #pragma unroll
      for (int j = 0; j < NFL; ++j) out[j] = bf2f(u[j]);
    } else {
      us4v u = *(const us4v*)p;
      #pragma unroll
      for (int j = 0; j < NFL; ++j) out[j] = bf2f(u[j]);
    }
  } else {
    const float* p = (const float*)xg + (size_t)s * FIN + f0;
    #pragma unroll
    for (int j = 0; j < NFL; ++j) out[j] = p[j];
  }
}

template<int FIN, bool BF, int STR>
__device__ __forceinline__ void aggr_phase1(const void* __restrict__ xg,
    const float* __restrict__ alpha_s, const float* __restrict__ alpha_d,
    const int* __restrict__ fill, const unsigned short* __restrict__ csr,
    _Float16* __restrict__ ylds, int base, int w, int l)
{
  const int NFL = FIN / 16;                       // features per lane
  const int h = l >> 4, sub = l & 15, f0 = sub * NFL;
  #pragma unroll 1
  for (int r = 0; r < 4; ++r){
    const int n = base + w * 4 + r;
    const float adv = alpha_d[n * 4 + h];
    float den = 0.f;
    float acc[NFL];
    #pragma unroll
    for (int j = 0; j < NFL; ++j) acc[j] = 0.f;

    int cnt = fill[(unsigned)n * FILLSTR]; if (cnt > CAP) cnt = CAP;
    const unsigned short* cp = csr + ((unsigned)n << 6);
    int p = 0;
    for (; p + 8 <= cnt; p += 8){                 // 8-edge batch
      ushort8 s8 = *(const ushort8*)(cp + p);     // 16B broadcast
      float a[8];
      float v[8][NFL];
      #pragma unroll
      for (int i = 0; i < 8; ++i){
        unsigned s = s8[i];
        a[i] = alpha_s[s * 4 + h];
        ldrow<FIN, BF>(xg, s, f0, v[i]);
      }
      #pragma unroll
      for (int i = 0; i < 8; ++i){
        float e = a[i] + adv; e = fmaxf(e, 0.2f * e); float wt = __expf(e);
        den += wt;
        #pragma unroll
        for (int j = 0; j < NFL; ++j) acc[j] += wt * v[i][j];
      }
    }
    if (p + 4 <= cnt){                            // 4-edge batch
      ushort4 s4 = *(const ushort4*)(cp + p);
      unsigned sx = s4.x, sy = s4.y, sz = s4.z, sw = s4.w;
      float ax = alpha_s[sx * 4 + h];
      float ay = alpha_s[sy * 4 + h];
      float az = alpha_s[sz * 4 + h];
      float aw = alpha_s[sw * 4 + h];
      float vx[NFL], vy[NFL], vz[NFL], vw[NFL];
      ldrow<FIN, BF>(xg, sx, f0, vx);
      ldrow<FIN, BF>(xg, sy, f0, vy);
      ldrow<FIN, BF>(xg, sz, f0, vz);
      ldrow<FIN, BF>(xg, sw, f0, vw);
      float e0 = ax + adv; e0 = fmaxf(e0, 0.2f * e0); float w0 = __expf(e0);
      float e1 = ay + adv; e1 = fmaxf(e1, 0.2f * e1); float w1 = __expf(e1);
      float e2 = az + adv; e2 = fmaxf(e2, 0.2f * e2); float w2 = __expf(e2);
      float e3 = aw + adv; e3 = fmaxf(e3, 0.2f * e3); float w3 = __expf(e3);
      den += w0; den += w1; den += w2; den += w3;
      #pragma unroll
      for (int j = 0; j < NFL; ++j)
        acc[j] += w0 * vx[j] + w1 * vy[j] + w2 * vz[j] + w3 * vw[j];
      p += 4;
    }
    for (; p < cnt; ++p){                         // scalar tail (<4)
      unsigned s = cp[p];
      float a = alpha_s[s * 4 + h];
      float v0[NFL];
      ldrow<FIN, BF>(xg, s, f0, v0);
      float e = a + adv; e = fmaxf(e, 0.2f * e); float wgt = __expf(e);
      den += wgt;
      #pragma unroll
      for (int j = 0; j < NFL; ++j) acc[j] += wgt * v0[j];
    }
    const float rh = (den > 0.f) ? (1.f / den) : 0.f;
    const int row = w * 4 + r;
    _Float16* yp = &ylds[row * STR + h * FIN + f0];
    #pragma unroll
    for (int j = 0; j < NFL; ++j) yp[j] = (_Float16)(acc[j] * rh);
  }
}

template<int FIN, int MODE>
__global__ __launch_bounds__(256) void k_aggrX(
    const void* __restrict__ xg,                 // [N, FIN] bf16 (or fp32 if MODE 0 && !flag)
    const float* __restrict__ alpha_s, const float* __restrict__ alpha_d,
    const int* __restrict__ fill, const unsigned short* __restrict__ csr,
    const _Float16* __restrict__ Wf,             // f16 B-frags, NT=4, KT=FIN/8
    const float* __restrict__ bias, void* __restrict__ out,
    const int* __restrict__ flag)
{
  const int K = 4 * FIN, KT = K / 32, STR = K + 8;
  __shared__ _Float16 ylds[16 * (4 * FIN + 8)];
  const int tid = threadIdx.x, w = tid >> 6, l = tid & 63;
  const int base = blockIdx.x * 16;               // N divisible by 16

  if (MODE == 0 && *flag == 0)
    aggr_phase1<FIN, false, STR>(xg, alpha_s, alpha_d, fill, csr, ylds, base, w, l);
  else
    aggr_phase1<FIN, true,  STR>(xg, alpha_s, alpha_d, fill, csr, ylds, base, w, l);
  __syncthreads();

  const int quad = l >> 4, m = l & 15;
  const int nt = w;                               // wave w -> output cols nt*16..
  f32x4 cacc = (f32x4)0.f;
  #pragma unroll
  for (int kt = 0; kt < KT; ++kt){
    f16x8 av = *(const f16x8*)&ylds[m * STR + kt * 32 + quad * 8];
    f16x8 bv = *(const f16x8*)(Wf + ((size_t)(nt * KT + kt) * 64 + l) * 8);
    cacc = __builtin_amdgcn_mfma_f32_16x16x32_f16(av, bv, cacc, 0, 0, 0);
  }
  const int c = nt * 16 + m;
  const float bs = bias[c];
  #pragma unroll
  for (int r2 = 0; r2 < 4; ++r2){
    int node = base + quad * 4 + r2;
    float v = cacc[r2] + bs;
    v = fmaxf(v, 0.1f * v);                       // post-layer leaky 0.1
    if (MODE == 0){
      ((unsigned short*)out)[(size_t)node * 64 + c] = f2bf(v);
    } else {
      if (*flag) ((unsigned short*)out)[(size_t)node * 64 + c] = f2bf(v);
      else       ((float*)out)[(size_t)node * 64 + c] = v;
    }
  }
}

// ---------------- launch ----------------

extern "C" void kernel_launch(void* const* d_in, const int* in_sizes, int n_in,
                              void* d_out, int out_size, void* d_ws, size_t ws_size,
                              hipStream_t stream)
{
  const void* x  = d_in[0];
  const int* ei  = (const int*)d_in[1];
  const int* src = ei;
  const int* dst = ei + N_EDGES;

  char* ws = (char*)d_ws;                      // footprint ~17.7 MB
  unsigned short* csr = (unsigned short*)(ws);             // [N*64] ushort padded CSR (6.4 MB)
  unsigned short* x2  = (unsigned short*)(ws + 6400000);   // [N,64] bf16 layer-1 out (6.4 MB)
  float* as_    = (float*)(ws + 12800000);     // [N,4]
  float* ad_    = (float*)(ws + 13600000);     // [N,4]
  int*   fill   = (int*)  (ws + 14400000);     // [N*16] padded counters (3.2 MB)
  _Float16* Wb1f = (_Float16*)(ws + 17600000); // [32768] f16 stacked-W1 frags
  _Float16* Wb2f = (_Float16*)(ws + 17665536); // [16384] f16 stacked-W2 frags
  unsigned short* Bsd1f = (unsigned short*)(ws + 17698304);  // [2048] bf16
  unsigned short* Bsd2f = (unsigned short*)(ws + 17702400);  // [1024] bf16
  float* bc1    = (float*)(ws + 17704448);     // [64]
  float* bc2    = (float*)(ws + 17704704);     // [64]
  int*   flag   = (int*)  (ws + 17704960);     // dtype flag (1 = bf16)

  hipMemsetAsync(fill, 0, N_NODES * FILLSTR * sizeof(int), stream);

  SetupPtrs S;
  S.W1 = d_in[2];  S.A1 = d_in[3];  S.aS1 = d_in[4];  S.aD1 = d_in[5];  S.b1 = d_in[6];
  S.W2 = d_in[7];  S.A2 = d_in[8];  S.aS2 = d_in[9];  S.aD2 = d_in[10]; S.b2 = d_in[11];
  S.x  = x;
  k_setup<<<205, 256, 0, stream>>>(S, Wb1f, Wb2f, Bsd1f, Bsd2f, bc1, bc2, flag);

  // scatter (782 blocks, 4 edges/thread) || layer-1 alpha (782 blocks)
  k_scatter_nodeA1<<<NB_SC4 + NB_NODE1, 256, 0, stream>>>(
      src, dst, fill, csr, x, Bsd1f, as_, ad_, flag);

  // layer 1: weighted-x aggregation + stacked-W1 MFMA -> x2 bf16
  k_aggrX<128, 0><<<N_NODES / 16, 256, 0, stream>>>(
      x, as_, ad_, fill, csr, Wb1f, bc1, x2, flag);

  // layer-2 alpha from x2 (always bf16)
  k_nodeA<64, false><<<NB_NODE1, 256, 0, stream>>>(x2, Bsd2f, as_, ad_, flag);

  // layer 2: aggregation + stacked-W2 MFMA -> final out
  k_aggrX<64, 1><<<N_NODES / 16, 256, 0, stream>>>(
      x2, as_, ad_, fill, csr, Wb2f, bc2, d_out, flag);
}

// Round 9
// 284.059 us; speedup vs baseline: 1.1919x; 1.0404x over previous
//
#include <hip/hip_runtime.h>

// GAT 2-layer fused pipeline for MI355X.
// N=50000 nodes, E=800000 edges, H=4 heads, C=64 channels, D=4 att dims.
// Inputs bf16 (runtime-detected, fp32 fallback); edge_index int32.
//
// Round-23 = r19 (proven 291.5 us; r22 fill-padding neutral, reverted) + ONE
// change: UNIQUE-LANE gather for the layer-1 aggregation (FIN=128).
//   Evidence: r15's aggr sustained 3.36 TB/s on the same 195 MB of scattered
//   fetches with 64x8B distinct lane addresses; the r18/r19 head-group layout
//   (4 groups re-reading the same 4 lines, 4x duplicated addresses) gets only
//   2.35 TB/s. New layout: lane l owns features {2l,2l+1} (one 4B dword per
//   edge, every line requested once). Head weights w_h are computed one-exp-
//   per-lane as before (group h) and distributed via readlane (SALU). Same
//   multiply-add sequence per (head,feature) -> ylds bitwise identical,
//   absmax 1.2207e-4. Layer 2 (FIN=64) keeps the proven r19 path.

#define N_NODES 50000
#define N_EDGES 800000
#define CAP 64        // padded-CSR per-node capacity (max degree ~40 here)
#define NB_SC4 782    // ceil(N_EDGES/1024) scatter blocks (4 edges/thread)
#define NB_NODE1 782  // ceil(N_NODES/64) nodeA blocks

typedef __attribute__((ext_vector_type(8))) short short8;       // 8 bf16
typedef __attribute__((ext_vector_type(8))) _Float16 f16x8;     // 8 fp16
typedef __attribute__((ext_vector_type(2))) _Float16 f16x2;
typedef __attribute__((ext_vector_type(4))) float f32x4;
typedef __attribute__((ext_vector_type(8))) unsigned short ushort8;
typedef __attribute__((ext_vector_type(4))) unsigned short us4v;

__device__ __forceinline__ float bf2f(unsigned short u){
  return __uint_as_float(((unsigned int)u) << 16);
}
__device__ __forceinline__ unsigned short f2bf(float f){
  unsigned int u = __float_as_uint(f);
  u = (u + 0x7FFFu + ((u >> 16) & 1u)) >> 16;   // round-to-nearest-even
  return (unsigned short)u;
}
__device__ __forceinline__ float ldf(const void* p, int i, bool bf){
  return bf ? bf2f(((const unsigned short*)p)[i]) : ((const float*)p)[i];
}
__device__ __forceinline__ float rdlane(float v, int lane){
  return __uint_as_float(__builtin_amdgcn_readlane(__float_as_uint(v), lane));
}

// ---------------- weight prep (205 blocks) + dtype flag ----------------
// Blocks 0..127: W1' stacked-f16 frags; 128..191: W2'; 192..199: Bsd1 (bf16);
// 200..203: Bsd2; 204: bias copies + flag. Dtype self-detected per block.
// Stacked weight: W'[q, c] = 0.25*W[f, h*64+c], q = h*Fin+f  (head-mean folded).
// B-frag layout (mfma 16x16x32): Wf[((nt*KT+kt)*64+lane)*8+j] =
//   W'[q = kt*32+(lane>>4)*8+j][c = nt*16+(lane&15)], NT=4.
struct SetupPtrs {
  const void *W1, *A1, *aS1, *aD1, *b1, *W2, *A2, *aS2, *aD2, *b2, *x;
};

__global__ __launch_bounds__(256) void k_setup(SetupPtrs S,
    _Float16* __restrict__ Wb1f, _Float16* __restrict__ Wb2f,
    unsigned short* __restrict__ Bsd1f, unsigned short* __restrict__ Bsd2f,
    float* __restrict__ bc1, float* __restrict__ bc2,
    int* __restrict__ flag)
{
  __shared__ int sbf;
  const int tid = threadIdx.x;
  if (tid < 64){                                  // wave 0: dtype probe
    unsigned int w = ((const unsigned int*)S.x)[tid] & 0xFFFFu;
    unsigned int e = (w >> 7) & 0xFFu;
    bool hit = (e >= 100u && e <= 135u);
    unsigned long long m = __ballot(hit);
    if (tid == 0) sbf = (__popcll(m) > 40) ? 1 : 0;
  }
  __syncthreads();
  const bool bf = (sbf != 0);
  const int bw = blockIdx.x;
  if (bw < 128){                                  // W1' (K=512, KT=16): 32768 elems
    int t = bw * 256 + tid;
    int j = t & 7, lane = (t >> 3) & 63, kt = (t >> 9) & 15, nt = t >> 13;
    int q = kt * 32 + (lane >> 4) * 8 + j;        // 0..511
    int c = nt * 16 + (lane & 15);
    int h = q >> 7, f = q & 127;
    Wb1f[t] = (_Float16)(0.25f * ldf(S.W1, f * 256 + h * 64 + c, bf));
  } else if (bw < 192){                           // W2' (K=256, KT=8): 16384 elems
    int t = (bw - 128) * 256 + tid;
    int j = t & 7, lane = (t >> 3) & 63, kt = (t >> 9) & 7, nt = t >> 12;
    int q = kt * 32 + (lane >> 4) * 8 + j;        // 0..255
    int c = nt * 16 + (lane & 15);
    int h = q >> 6, f = q & 63;
    Wb2f[t] = (_Float16)(0.25f * ldf(S.W2, f * 256 + h * 64 + c, bf));
  } else if (bw < 200){                           // Bsd1 fragments: 2048 elems (kt<4)
    int t = (bw - 192) * 256 + tid;
    int j = t & 7, lane = (t >> 3) & 63, kt = t >> 9;
    int k = kt * 32 + (lane >> 4) * 8 + j;
    int c = lane & 15;
    float v = 0.f;
    if (c < 4){
      for (int dd = 0; dd < 4; ++dd)
        v += ldf(S.A1, k * 16 + c * 4 + dd, bf) * ldf(S.aS1, c * 4 + dd, bf);
    } else if (c < 8){
      int h = c - 4;
      for (int dd = 0; dd < 4; ++dd)
        v += ldf(S.A1, k * 16 + h * 4 + dd, bf) * ldf(S.aD1, h * 4 + dd, bf);
    }
    Bsd1f[t] = f2bf(v);
  } else if (bw < 204){                           // Bsd2 fragments: 1024 elems (kt<2)
    int t = (bw - 200) * 256 + tid;
    int j = t & 7, lane = (t >> 3) & 63, kt = t >> 9;
    int k = kt * 32 + (lane >> 4) * 8 + j;
    int c = lane & 15;
    float v = 0.f;
    if (c < 4){
      for (int dd = 0; dd < 4; ++dd)
        v += ldf(S.A2, k * 16 + c * 4 + dd, bf) * ldf(S.aS2, c * 4 + dd, bf);
    } else if (c < 8){
      int h = c - 4;
      for (int dd = 0; dd < 4; ++dd)
        v += ldf(S.A2, k * 16 + h * 4 + dd, bf) * ldf(S.aD2, h * 4 + dd, bf);
    }
    Bsd2f[t] = f2bf(v);
  } else {                                        // bias copies + flag
    if (tid < 64)       bc1[tid] = ldf(S.b1, tid, bf);
    else if (tid < 128) bc2[tid - 64] = ldf(S.b2, tid - 64, bf);
    else if (tid == 128) *flag = bf ? 1 : 0;
  }
}

// ---------------- alpha transform ----------------

template<int F, bool DYN>
__device__ __forceinline__ void nodeA_body(int nblk, int tid,
    const void* __restrict__ xin_, const unsigned short* __restrict__ Bsdf,
    float* __restrict__ alpha_s, float* __restrict__ alpha_d,
    const int* __restrict__ flag)
{
  const int STR = F + 8;                   // row stride in ushorts (16B pad)
  const int KT  = F / 32;
  const int CH  = F / 8;
  __shared__ unsigned short xs[64 * (F + 8)];
  const int base = nblk * 64;
  bool bf = true;
  if (DYN) bf = (*flag != 0);
  for (int v = tid; v < 64 * CH; v += 256){
    int row = v / CH, c8 = v % CH;
    int node = base + row; if (node >= N_NODES) node = N_NODES - 1;
    size_t g = (size_t)node * F + c8 * 8;
    ushort8 u;
    if (!DYN || bf){
      u = *(const ushort8*)((const unsigned short*)xin_ + g);
    } else {
      const float* xf = (const float*)xin_ + g;
      float4 f0 = *(const float4*)xf, f1 = *(const float4*)(xf + 4);
      u[0]=f2bf(f0.x); u[1]=f2bf(f0.y); u[2]=f2bf(f0.z); u[3]=f2bf(f0.w);
      u[4]=f2bf(f1.x); u[5]=f2bf(f1.y); u[6]=f2bf(f1.z); u[7]=f2bf(f1.w);
    }
    *(ushort8*)&xs[row * STR + c8 * 8] = u;
  }
  __syncthreads();

  const int wave = tid >> 6, l = tid & 63;
  const int quad = l >> 4, m = l & 15;
  const int wbase = base + wave * 16;

  f32x4 aacc = (f32x4)0.f;
  #pragma unroll
  for (int kt = 0; kt < KT; ++kt){
    short8 af = *(const short8*)&xs[(wave * 16 + m) * STR + kt * 32 + quad * 8];
    short8 sdfrag = *(const short8*)(Bsdf + ((size_t)kt * 64 + l) * 8);
    aacc = __builtin_amdgcn_mfma_f32_16x16x32_bf16(af, sdfrag, aacc, 0, 0, 0);
  }
  if (m < 8){
    float* dstp = (m < 4) ? alpha_s : alpha_d;
    int hh = m & 3;
    #pragma unroll
    for (int r = 0; r < 4; ++r){
      int node = wbase + quad * 4 + r;
      if (node < N_NODES) dstp[node * 4 + hh] = aacc[r];
    }
  }
}

// ---------------- fused padded-CSR scatter (ushort, 4-edge ILP) + layer-1 alpha ----------------

__global__ __launch_bounds__(256) void k_scatter_nodeA1(
    const int* __restrict__ src, const int* __restrict__ dst,
    int* __restrict__ fill, unsigned short* __restrict__ csr,
    const void* __restrict__ xin_, const unsigned short* __restrict__ Bsdf,
    float* __restrict__ alpha_s, float* __restrict__ alpha_d,
    const int* __restrict__ flag)
{
  const int b = blockIdx.x, tid = threadIdx.x;
  if (b < NB_SC4){
    const int ebase = b * 1024 + tid;
    int d[4], s[4];
    #pragma unroll
    for (int i = 0; i < 4; ++i){
      int e = ebase + i * 256;
      bool ok = (e < N_EDGES);
      d[i] = ok ? dst[e] : -1;
      s[i] = ok ? src[e] : 0;
    }
    #pragma unroll
    for (int i = 0; i < 4; ++i){
      if (d[i] >= 0){
        int r = atomicAdd(&fill[d[i]], 1);
        if (r < CAP) csr[((unsigned)d[i] << 6) + r] = (unsigned short)s[i];
      }
    }
    return;
  }
  nodeA_body<128, true>(b - NB_SC4, tid, xin_, Bsdf, alpha_s, alpha_d, flag);
}

// standalone layer-2 alpha kernel (x2 is always bf16)
template<int F, bool DYN>
__global__ __launch_bounds__(256) void k_nodeA(const void* __restrict__ xin_,
    const unsigned short* __restrict__ Bsdf,
    float* __restrict__ alpha_s, float* __restrict__ alpha_d,
    const int* __restrict__ flag)
{
  nodeA_body<F, DYN>(blockIdx.x, threadIdx.x, xin_, Bsdf, alpha_s, alpha_d, flag);
}

// ---------------- weighted-feature aggregation + stacked-W MFMA epilogue ----------------
// Block = 256 thr = 4 waves, 16 dst nodes (wave w owns nodes base+4w..base+4w+3).
//
// FIN=128 phase 1 (r23, unique-lane): lane l owns features {2l,2l+1} (one 4B
//   dword per edge, all 64 lanes' lines distinct -> clean coalescing). Group
//   h = l>>4 computes w_h (one exp chain/lane); readlane distributes w_0..3;
//   each lane accumulates acc[4][2]. ylds bitwise identical to r19.
// FIN=64 phase 1 (r19): head-group layout, lane owns 4 features of head l>>4.
//
// Phase 2: wave w computes output n-tile nt=w of [16 nodes]x[K=4*FIN]@W'[K,64]
//   via KT f16 MFMAs; + bias, leaky 0.1, store.
// MODE 0: layer 1 — x gather dtype per flag; out x2 bf16.
// MODE 1: layer 2 — x2 always bf16; out per flag (bf16 else fp32).

template<int FIN, bool BF>
__device__ __forceinline__ void ldrow(const void* xg, unsigned s, int f0,
                                      float (&out)[FIN / 16])
{
  const int NFL = FIN / 16;
  if (BF){
    const unsigned short* p = (const unsigned short*)xg + (size_t)s * FIN + f0;
    if (NFL == 8){
      ushort8 u = *(const ushort8*)p;
      #pragma unroll
      for (int j = 0; j < NFL; ++j) out[j] = bf2f(u[j]);
    } else {
      us4v u = *(const us4v*)p;
      #pragma unroll
      for (int j = 0; j < NFL; ++j) out[j] = bf2f(u[j]);
    }
  } else {
    const float* p = (const float*)xg + (size_t)s * FIN + f0;
    #pragma unroll
    for (int j = 0; j < NFL; ++j) out[j] = p[j];
  }
}

// ---- unique-lane phase 1 for FIN=128 ----
template<bool BF, int STR>
__device__ __forceinline__ void aggr_phase1_u128(const void* __restrict__ xg,
    const float* __restrict__ alpha_s, const float* __restrict__ alpha_d,
    const int* __restrict__ fill, const unsigned short* __restrict__ csr,
    _Float16* __restrict__ ylds, int base, int w, int l)
{
  const int h = l >> 4;                           // own head for exp chain
  #pragma unroll 1
  for (int r = 0; r < 4; ++r){
    const int n = base + w * 4 + r;
    const float adv = alpha_d[n * 4 + h];
    float den = 0.f;
    float acc[4][2];
    #pragma unroll
    for (int hh = 0; hh < 4; ++hh){ acc[hh][0] = 0.f; acc[hh][1] = 0.f; }

    int cnt = fill[n]; if (cnt > CAP) cnt = CAP;
    const unsigned short* cp = csr + ((unsigned)n << 6);
    int p = 0;
    for (; p + 8 <= cnt; p += 8){                 // 8-edge batch
      ushort8 s8 = *(const ushort8*)(cp + p);     // 16B broadcast
      float a[8];
      float lo[8], hi[8];
      #pragma unroll
      for (int i = 0; i < 8; ++i){
        unsigned s = s8[i];
        a[i] = alpha_s[s * 4 + h];
        if (BF){
          unsigned xv = *(const unsigned int*)((const unsigned short*)xg + (size_t)s * 128 + 2 * l);
          lo[i] = bf2f((unsigned short)(xv & 0xFFFFu));
          hi[i] = bf2f((unsigned short)(xv >> 16));
        } else {
          const float* xf = (const float*)xg + (size_t)s * 128 + 2 * l;
          lo[i] = xf[0]; hi[i] = xf[1];
        }
      }
      #pragma unroll
      for (int i = 0; i < 8; ++i){
        float e = a[i] + adv; e = fmaxf(e, 0.2f * e); float wt = __expf(e);
        den += wt;
        float w0 = rdlane(wt, 0),  w1 = rdlane(wt, 16);
        float w2 = rdlane(wt, 32), w3 = rdlane(wt, 48);
        acc[0][0] += w0 * lo[i]; acc[0][1] += w0 * hi[i];
        acc[1][0] += w1 * lo[i]; acc[1][1] += w1 * hi[i];
        acc[2][0] += w2 * lo[i]; acc[2][1] += w2 * hi[i];
        acc[3][0] += w3 * lo[i]; acc[3][1] += w3 * hi[i];
      }
    }
    if (p + 4 <= cnt){                            // 4-edge batch
      ushort4 s4 = *(const ushort4*)(cp + p);
      unsigned ss[4] = {s4.x, s4.y, s4.z, s4.w};
      float a[4], lo[4], hi[4];
      #pragma unroll
      for (int i = 0; i < 4; ++i){
        a[i] = alpha_s[ss[i] * 4 + h];
        if (BF){
          unsigned xv = *(const unsigned int*)((const unsigned short*)xg + (size_t)ss[i] * 128 + 2 * l);
          lo[i] = bf2f((unsigned short)(xv & 0xFFFFu));
          hi[i] = bf2f((unsigned short)(xv >> 16));
        } else {
          const float* xf = (const float*)xg + (size_t)ss[i] * 128 + 2 * l;
          lo[i] = xf[0]; hi[i] = xf[1];
        }
      }
      #pragma unroll
      for (int i = 0; i < 4; ++i){
        float e = a[i] + adv; e = fmaxf(e, 0.2f * e); float wt = __expf(e);
        den += wt;
        float w0 = rdlane(wt, 0),  w1 = rdlane(wt, 16);
        float w2 = rdlane(wt, 32), w3 = rdlane(wt, 48);
        acc[0][0] += w0 * lo[i]; acc[0][1] += w0 * hi[i];
        acc[1][0] += w1 * lo[i]; acc[1][1] += w1 * hi[i];
        acc[2][0] += w2 * lo[i]; acc[2][1] += w2 * hi[i];
        acc[3][0] += w3 * lo[i]; acc[3][1] += w3 * hi[i];
      }
      p += 4;
    }
    for (; p < cnt; ++p){                         // scalar tail (<4)
      unsigned s = cp[p];
      float a = alpha_s[s * 4 + h];
      float lo, hi;
      if (BF){
        unsigned xv = *(const unsigned int*)((const unsigned short*)xg + (size_t)s * 128 + 2 * l);
        lo = bf2f((unsigned short)(xv & 0xFFFFu));
        hi = bf2f((unsigned short)(xv >> 16));
      } else {
        const float* xf = (const float*)xg + (size_t)s * 128 + 2 * l;
        lo = xf[0]; hi = xf[1];
      }
      float e = a + adv; e = fmaxf(e, 0.2f * e); float wt = __expf(e);
      den += wt;
      float w0 = rdlane(wt, 0),  w1 = rdlane(wt, 16);
      float w2 = rdlane(wt, 32), w3 = rdlane(wt, 48);
      acc[0][0] += w0 * lo; acc[0][1] += w0 * hi;
      acc[1][0] += w1 * lo; acc[1][1] += w1 * hi;
      acc[2][0] += w2 * lo; acc[2][1] += w2 * hi;
      acc[3][0] += w3 * lo; acc[3][1] += w3 * hi;
    }
    // per-head denominators (identical within each group) -> all lanes
    float d0 = rdlane(den, 0),  d1 = rdlane(den, 16);
    float d2 = rdlane(den, 32), d3 = rdlane(den, 48);
    float rh0 = (d0 > 0.f) ? (1.f / d0) : 0.f;
    float rh1 = (d1 > 0.f) ? (1.f / d1) : 0.f;
    float rh2 = (d2 > 0.f) ? (1.f / d2) : 0.f;
    float rh3 = (d3 > 0.f) ? (1.f / d3) : 0.f;
    const int row = w * 4 + r;
    _Float16* yp = &ylds[row * STR + 2 * l];
    *(f16x2*)(yp +   0) = (f16x2){(_Float16)(acc[0][0] * rh0), (_Float16)(acc[0][1] * rh0)};
    *(f16x2*)(yp + 128) = (f16x2){(_Float16)(acc[1][0] * rh1), (_Float16)(acc[1][1] * rh1)};
    *(f16x2*)(yp + 256) = (f16x2){(_Float16)(acc[2][0] * rh2), (_Float16)(acc[2][1] * rh2)};
    *(f16x2*)(yp + 384) = (f16x2){(_Float16)(acc[3][0] * rh3), (_Float16)(acc[3][1] * rh3)};
  }
}

// ---- r19 head-group phase 1 (used for FIN=64) ----
template<int FIN, bool BF, int STR>
__device__ __forceinline__ void aggr_phase1(const void* __restrict__ xg,
    const float* __restrict__ alpha_s, const float* __restrict__ alpha_d,
    const int* __restrict__ fill, const unsigned short* __restrict__ csr,
    _Float16* __restrict__ ylds, int base, int w, int l)
{
  const int NFL = FIN / 16;                       // features per lane
  const int h = l >> 4, sub = l & 15, f0 = sub * NFL;
  #pragma unroll 1
  for (int r = 0; r < 4; ++r){
    const int n = base + w * 4 + r;
    const float adv = alpha_d[n * 4 + h];
    float den = 0.f;
    float acc[NFL];
    #pragma unroll
    for (int j = 0; j < NFL; ++j) acc[j] = 0.f;

    int cnt = fill[n]; if (cnt > CAP) cnt = CAP;
    const unsigned short* cp = csr + ((unsigned)n << 6);
    int p = 0;
    for (; p + 8 <= cnt; p += 8){                 // 8-edge batch
      ushort8 s8 = *(const ushort8*)(cp + p);     // 16B broadcast
      float a[8];
      float v[8][NFL];
      #pragma unroll
      for (int i = 0; i < 8; ++i){
        unsigned s = s8[i];
        a[i] = alpha_s[s * 4 + h];
        ldrow<FIN, BF>(xg, s, f0, v[i]);
      }
      #pragma unroll
      for (int i = 0; i < 8; ++i){
        float e = a[i] + adv; e = fmaxf(e, 0.2f * e); float wt = __expf(e);
        den += wt;
        #pragma unroll
        for (int j = 0; j < NFL; ++j) acc[j] += wt * v[i][j];
      }
    }
    if (p + 4 <= cnt){                            // 4-edge batch
      ushort4 s4 = *(const ushort4*)(cp + p);
      unsigned sx = s4.x, sy = s4.y, sz = s4.z, sw = s4.w;
      float ax = alpha_s[sx * 4 + h];
      float ay = alpha_s[sy * 4 + h];
      float az = alpha_s[sz * 4 + h];
      float aw = alpha_s[sw * 4 + h];
      float vx[NFL], vy[NFL], vz[NFL], vw[NFL];
      ldrow<FIN, BF>(xg, sx, f0, vx);
      ldrow<FIN, BF>(xg, sy, f0, vy);
      ldrow<FIN, BF>(xg, sz, f0, vz);
      ldrow<FIN, BF>(xg, sw, f0, vw);
      float e0 = ax + adv; e0 = fmaxf(e0, 0.2f * e0); float w0 = __expf(e0);
      float e1 = ay + adv; e1 = fmaxf(e1, 0.2f * e1); float w1 = __expf(e1);
      float e2 = az + adv; e2 = fmaxf(e2, 0.2f * e2); float w2 = __expf(e2);
      float e3 = aw + adv; e3 = fmaxf(e3, 0.2f * e3); float w3 = __expf(e3);
      den += w0; den += w1; den += w2; den += w3;
      #pragma unroll
      for (int j = 0; j < NFL; ++j)
        acc[j] += w0 * vx[j] + w1 * vy[j] + w2 * vz[j] + w3 * vw[j];
      p += 4;
    }
    for (; p < cnt; ++p){                         // scalar tail (<4)
      unsigned s = cp[p];
      float a = alpha_s[s * 4 + h];
      float v0[NFL];
      ldrow<FIN, BF>(xg, s, f0, v0);
      float e = a + adv; e = fmaxf(e, 0.2f * e); float wgt = __expf(e);
      den += wgt;
      #pragma unroll
      for (int j = 0; j < NFL; ++j) acc[j] += wgt * v0[j];
    }
    const float rh = (den > 0.f) ? (1.f / den) : 0.f;
    const int row = w * 4 + r;
    _Float16* yp = &ylds[row * STR + h * FIN + f0];
    #pragma unroll
    for (int j = 0; j < NFL; ++j) yp[j] = (_Float16)(acc[j] * rh);
  }
}

template<int FIN, int MODE>
__global__ __launch_bounds__(256) void k_aggrX(
    const void* __restrict__ xg,                 // [N, FIN] bf16 (or fp32 if MODE 0 && !flag)
    const float* __restrict__ alpha_s, const float* __restrict__ alpha_d,
    const int* __restrict__ fill, const unsigned short* __restrict__ csr,
    const _Float16* __restrict__ Wf,             // f16 B-frags, NT=4, KT=FIN/8
    const float* __restrict__ bias, void* __restrict__ out,
    const int* __restrict__ flag)
{
  const int K = 4 * FIN, KT = K / 32, STR = K + 8;
  __shared__ _Float16 ylds[16 * (4 * FIN + 8)];
  const int tid = threadIdx.x, w = tid >> 6, l = tid & 63;
  const int base = blockIdx.x * 16;               // N divisible by 16

  if (FIN == 128){
    if (MODE == 0 && *flag == 0)
      aggr_phase1_u128<false, STR>(xg, alpha_s, alpha_d, fill, csr, ylds, base, w, l);
    else
      aggr_phase1_u128<true,  STR>(xg, alpha_s, alpha_d, fill, csr, ylds, base, w, l);
  } else {
    if (MODE == 0 && *flag == 0)
      aggr_phase1<FIN, false, STR>(xg, alpha_s, alpha_d, fill, csr, ylds, base, w, l);
    else
      aggr_phase1<FIN, true,  STR>(xg, alpha_s, alpha_d, fill, csr, ylds, base, w, l);
  }
  __syncthreads();

  const int quad = l >> 4, m = l & 15;
  const int nt = w;                               // wave w -> output cols nt*16..
  f32x4 cacc = (f32x4)0.f;
  #pragma unroll
  for (int kt = 0; kt < KT; ++kt){
    f16x8 av = *(const f16x8*)&ylds[m * STR + kt * 32 + quad * 8];
    f16x8 bv = *(const f16x8*)(Wf + ((size_t)(nt * KT + kt) * 64 + l) * 8);
    cacc = __builtin_amdgcn_mfma_f32_16x16x32_f16(av, bv, cacc, 0, 0, 0);
  }
  const int c = nt * 16 + m;
  const float bs = bias[c];
  #pragma unroll
  for (int r2 = 0; r2 < 4; ++r2){
    int node = base + quad * 4 + r2;
    float v = cacc[r2] + bs;
    v = fmaxf(v, 0.1f * v);                       // post-layer leaky 0.1
    if (MODE == 0){
      ((unsigned short*)out)[(size_t)node * 64 + c] = f2bf(v);
    } else {
      if (*flag) ((unsigned short*)out)[(size_t)node * 64 + c] = f2bf(v);
      else       ((float*)out)[(size_t)node * 64 + c] = v;
    }
  }
}

// ---------------- launch ----------------

extern "C" void kernel_launch(void* const* d_in, const int* in_sizes, int n_in,
                              void* d_out, int out_size, void* d_ws, size_t ws_size,
                              hipStream_t stream)
{
  const void* x  = d_in[0];
  const int* ei  = (const int*)d_in[1];
  const int* src = ei;
  const int* dst = ei + N_EDGES;

  char* ws = (char*)d_ws;                      // footprint ~14.7 MB
  unsigned short* csr = (unsigned short*)(ws);             // [N*64] ushort padded CSR (6.4 MB)
  unsigned short* x2  = (unsigned short*)(ws + 6400000);   // [N,64] bf16 layer-1 out (6.4 MB)
  float* as_    = (float*)(ws + 12800000);     // [N,4]
  float* ad_    = (float*)(ws + 13600000);     // [N,4]
  int*   fill   = (int*)  (ws + 14400000);     // [N] scatter atomics = degree
  _Float16* Wb1f = (_Float16*)(ws + 14600000); // [32768] f16 stacked-W1 frags
  _Float16* Wb2f = (_Float16*)(ws + 14665536); // [16384] f16 stacked-W2 frags
  unsigned short* Bsd1f = (unsigned short*)(ws + 14698304);  // [2048] bf16
  unsigned short* Bsd2f = (unsigned short*)(ws + 14702400);  // [1024] bf16
  float* bc1    = (float*)(ws + 14704448);     // [64]
  float* bc2    = (float*)(ws + 14704704);     // [64]
  int*   flag   = (int*)  (ws + 14704960);     // dtype flag (1 = bf16)

  hipMemsetAsync(fill, 0, N_NODES * sizeof(int), stream);

  SetupPtrs S;
  S.W1 = d_in[2];  S.A1 = d_in[3];  S.aS1 = d_in[4];  S.aD1 = d_in[5];  S.b1 = d_in[6];
  S.W2 = d_in[7];  S.A2 = d_in[8];  S.aS2 = d_in[9];  S.aD2 = d_in[10]; S.b2 = d_in[11];
  S.x  = x;
  k_setup<<<205, 256, 0, stream>>>(S, Wb1f, Wb2f, Bsd1f, Bsd2f, bc1, bc2, flag);

  // scatter (782 blocks, 4 edges/thread) || layer-1 alpha (782 blocks)
  k_scatter_nodeA1<<<NB_SC4 + NB_NODE1, 256, 0, stream>>>(
      src, dst, fill, csr, x, Bsd1f, as_, ad_, flag);

  // layer 1: weighted-x aggregation + stacked-W1 MFMA -> x2 bf16
  k_aggrX<128, 0><<<N_NODES / 16, 256, 0, stream>>>(
      x, as_, ad_, fill, csr, Wb1f, bc1, x2, flag);

  // layer-2 alpha from x2 (always bf16)
  k_nodeA<64, false><<<NB_NODE1, 256, 0, stream>>>(x2, Bsd2f, as_, ad_, flag);

  // layer 2: aggregation + stacked-W2 MFMA -> final out
  k_aggrX<64, 1><<<N_NODES / 16, 256, 0, stream>>>(
      x2, as_, ad_, fill, csr, Wb2f, bc2, d_out, flag);
}

// Round 10
// 277.077 us; speedup vs baseline: 1.2219x; 1.0252x over previous
//
#include <hip/hip_runtime.h>

// GAT 2-layer fused pipeline for MI355X.
// N=50000 nodes, E=800000 edges, H=4 heads, C=64 channels, D=4 att dims.
// Inputs bf16 (runtime-detected, fp32 fallback); edge_index int32.
//
// Round-24 = r23 (284.1 us) + two proven-pattern re-applications:
//   (a) nodeA64 fused into aggrX<128>'s epilogue (r20's verified code):
//       block stashes its 16-node x2 bf16 tile in LDS, wave 0 runs the
//       2-step Bsd2 MFMA, alphas2 -> separate as2/ad2. One dispatch fewer.
//   (b) unique-lane gather for aggrX<64> (mirror of r23's u128 win):
//       lane l owns feature l (one 2B ushort/edge, 64 lanes = the full
//       128B row once) vs head-group 4x line duplication. readlane
//       broadcasts head weights. ylds bitwise identical -> absmax
//       1.2207e-4 unchanged.
//   Scatter (77 us, atomic-latency floor across 4 variants) untouched.

#define N_NODES 50000
#define N_EDGES 800000
#define CAP 64        // padded-CSR per-node capacity (max degree ~40 here)
#define NB_SC4 782    // ceil(N_EDGES/1024) scatter blocks (4 edges/thread)
#define NB_NODE1 782  // ceil(N_NODES/64) nodeA blocks

typedef __attribute__((ext_vector_type(8))) short short8;       // 8 bf16
typedef __attribute__((ext_vector_type(8))) _Float16 f16x8;     // 8 fp16
typedef __attribute__((ext_vector_type(2))) _Float16 f16x2;
typedef __attribute__((ext_vector_type(4))) float f32x4;
typedef __attribute__((ext_vector_type(8))) unsigned short ushort8;
typedef __attribute__((ext_vector_type(4))) unsigned short us4v;

__device__ __forceinline__ float bf2f(unsigned short u){
  return __uint_as_float(((unsigned int)u) << 16);
}
__device__ __forceinline__ unsigned short f2bf(float f){
  unsigned int u = __float_as_uint(f);
  u = (u + 0x7FFFu + ((u >> 16) & 1u)) >> 16;   // round-to-nearest-even
  return (unsigned short)u;
}
__device__ __forceinline__ float ldf(const void* p, int i, bool bf){
  return bf ? bf2f(((const unsigned short*)p)[i]) : ((const float*)p)[i];
}
__device__ __forceinline__ float rdlane(float v, int lane){
  return __uint_as_float(__builtin_amdgcn_readlane(__float_as_uint(v), lane));
}

// ---------------- weight prep (205 blocks) + dtype flag ----------------
// Blocks 0..127: W1' stacked-f16 frags; 128..191: W2'; 192..199: Bsd1 (bf16);
// 200..203: Bsd2; 204: bias copies + flag. Dtype self-detected per block.
// Stacked weight: W'[q, c] = 0.25*W[f, h*64+c], q = h*Fin+f  (head-mean folded).
// B-frag layout (mfma 16x16x32): Wf[((nt*KT+kt)*64+lane)*8+j] =
//   W'[q = kt*32+(lane>>4)*8+j][c = nt*16+(lane&15)], NT=4.
struct SetupPtrs {
  const void *W1, *A1, *aS1, *aD1, *b1, *W2, *A2, *aS2, *aD2, *b2, *x;
};

__global__ __launch_bounds__(256) void k_setup(SetupPtrs S,
    _Float16* __restrict__ Wb1f, _Float16* __restrict__ Wb2f,
    unsigned short* __restrict__ Bsd1f, unsigned short* __restrict__ Bsd2f,
    float* __restrict__ bc1, float* __restrict__ bc2,
    int* __restrict__ flag)
{
  __shared__ int sbf;
  const int tid = threadIdx.x;
  if (tid < 64){                                  // wave 0: dtype probe
    unsigned int w = ((const unsigned int*)S.x)[tid] & 0xFFFFu;
    unsigned int e = (w >> 7) & 0xFFu;
    bool hit = (e >= 100u && e <= 135u);
    unsigned long long m = __ballot(hit);
    if (tid == 0) sbf = (__popcll(m) > 40) ? 1 : 0;
  }
  __syncthreads();
  const bool bf = (sbf != 0);
  const int bw = blockIdx.x;
  if (bw < 128){                                  // W1' (K=512, KT=16): 32768 elems
    int t = bw * 256 + tid;
    int j = t & 7, lane = (t >> 3) & 63, kt = (t >> 9) & 15, nt = t >> 13;
    int q = kt * 32 + (lane >> 4) * 8 + j;        // 0..511
    int c = nt * 16 + (lane & 15);
    int h = q >> 7, f = q & 127;
    Wb1f[t] = (_Float16)(0.25f * ldf(S.W1, f * 256 + h * 64 + c, bf));
  } else if (bw < 192){                           // W2' (K=256, KT=8): 16384 elems
    int t = (bw - 128) * 256 + tid;
    int j = t & 7, lane = (t >> 3) & 63, kt = (t >> 9) & 7, nt = t >> 12;
    int q = kt * 32 + (lane >> 4) * 8 + j;        // 0..255
    int c = nt * 16 + (lane & 15);
    int h = q >> 6, f = q & 63;
    Wb2f[t] = (_Float16)(0.25f * ldf(S.W2, f * 256 + h * 64 + c, bf));
  } else if (bw < 200){                           // Bsd1 fragments: 2048 elems (kt<4)
    int t = (bw - 192) * 256 + tid;
    int j = t & 7, lane = (t >> 3) & 63, kt = t >> 9;
    int k = kt * 32 + (lane >> 4) * 8 + j;
    int c = lane & 15;
    float v = 0.f;
    if (c < 4){
      for (int dd = 0; dd < 4; ++dd)
        v += ldf(S.A1, k * 16 + c * 4 + dd, bf) * ldf(S.aS1, c * 4 + dd, bf);
    } else if (c < 8){
      int h = c - 4;
      for (int dd = 0; dd < 4; ++dd)
        v += ldf(S.A1, k * 16 + h * 4 + dd, bf) * ldf(S.aD1, h * 4 + dd, bf);
    }
    Bsd1f[t] = f2bf(v);
  } else if (bw < 204){                           // Bsd2 fragments: 1024 elems (kt<2)
    int t = (bw - 200) * 256 + tid;
    int j = t & 7, lane = (t >> 3) & 63, kt = t >> 9;
    int k = kt * 32 + (lane >> 4) * 8 + j;
    int c = lane & 15;
    float v = 0.f;
    if (c < 4){
      for (int dd = 0; dd < 4; ++dd)
        v += ldf(S.A2, k * 16 + c * 4 + dd, bf) * ldf(S.aS2, c * 4 + dd, bf);
    } else if (c < 8){
      int h = c - 4;
      for (int dd = 0; dd < 4; ++dd)
        v += ldf(S.A2, k * 16 + h * 4 + dd, bf) * ldf(S.aD2, h * 4 + dd, bf);
    }
    Bsd2f[t] = f2bf(v);
  } else {                                        // bias copies + flag
    if (tid < 64)       bc1[tid] = ldf(S.b1, tid, bf);
    else if (tid < 128) bc2[tid - 64] = ldf(S.b2, tid - 64, bf);
    else if (tid == 128) *flag = bf ? 1 : 0;
  }
}

// ---------------- layer-1 alpha transform ----------------

__device__ __forceinline__ void nodeA_body(int nblk, int tid,
    const void* __restrict__ xin_, const unsigned short* __restrict__ Bsdf,
    float* __restrict__ alpha_s, float* __restrict__ alpha_d,
    const int* __restrict__ flag)
{
  const int F = 128, STR = F + 8, KT = 4, CH = F / 8;
  __shared__ unsigned short xs[64 * 136];
  const int base = nblk * 64;
  const bool bf = (*flag != 0);
  for (int v = tid; v < 64 * CH; v += 256){
    int row = v / CH, c8 = v % CH;
    int node = base + row; if (node >= N_NODES) node = N_NODES - 1;
    size_t g = (size_t)node * F + c8 * 8;
    ushort8 u;
    if (bf){
      u = *(const ushort8*)((const unsigned short*)xin_ + g);
    } else {
      const float* xf = (const float*)xin_ + g;
      float4 f0 = *(const float4*)xf, f1 = *(const float4*)(xf + 4);
      u[0]=f2bf(f0.x); u[1]=f2bf(f0.y); u[2]=f2bf(f0.z); u[3]=f2bf(f0.w);
      u[4]=f2bf(f1.x); u[5]=f2bf(f1.y); u[6]=f2bf(f1.z); u[7]=f2bf(f1.w);
    }
    *(ushort8*)&xs[row * STR + c8 * 8] = u;
  }
  __syncthreads();

  const int wave = tid >> 6, l = tid & 63;
  const int quad = l >> 4, m = l & 15;
  const int wbase = base + wave * 16;

  f32x4 aacc = (f32x4)0.f;
  #pragma unroll
  for (int kt = 0; kt < KT; ++kt){
    short8 af = *(const short8*)&xs[(wave * 16 + m) * STR + kt * 32 + quad * 8];
    short8 sdfrag = *(const short8*)(Bsdf + ((size_t)kt * 64 + l) * 8);
    aacc = __builtin_amdgcn_mfma_f32_16x16x32_bf16(af, sdfrag, aacc, 0, 0, 0);
  }
  if (m < 8){
    float* dstp = (m < 4) ? alpha_s : alpha_d;
    int hh = m & 3;
    #pragma unroll
    for (int r = 0; r < 4; ++r){
      int node = wbase + quad * 4 + r;
      if (node < N_NODES) dstp[node * 4 + hh] = aacc[r];
    }
  }
}

// ---------------- fused padded-CSR scatter (ushort, 4-edge ILP) + layer-1 alpha ----------------

__global__ __launch_bounds__(256) void k_scatter_nodeA1(
    const int* __restrict__ src, const int* __restrict__ dst,
    int* __restrict__ fill, unsigned short* __restrict__ csr,
    const void* __restrict__ xin_, const unsigned short* __restrict__ Bsdf,
    float* __restrict__ alpha_s, float* __restrict__ alpha_d,
    const int* __restrict__ flag)
{
  const int b = blockIdx.x, tid = threadIdx.x;
  if (b < NB_SC4){
    const int ebase = b * 1024 + tid;
    int d[4], s[4];
    #pragma unroll
    for (int i = 0; i < 4; ++i){
      int e = ebase + i * 256;
      bool ok = (e < N_EDGES);
      d[i] = ok ? dst[e] : -1;
      s[i] = ok ? src[e] : 0;
    }
    #pragma unroll
    for (int i = 0; i < 4; ++i){
      if (d[i] >= 0){
        int r = atomicAdd(&fill[d[i]], 1);
        if (r < CAP) csr[((unsigned)d[i] << 6) + r] = (unsigned short)s[i];
      }
    }
    return;
  }
  nodeA_body(b - NB_SC4, tid, xin_, Bsdf, alpha_s, alpha_d, flag);
}

// ---------------- weighted-feature aggregation + stacked-W MFMA epilogue ----------------
// Block = 256 thr = 4 waves, 16 dst nodes (wave w owns nodes base+4w..base+4w+3).
//
// Phase 1 (unique-lane, both layers): FIN=128: lane l owns features {2l,2l+1}
//   (4B dword/edge); FIN=64: lane l owns feature l (2B ushort/edge). All 64
//   lanes' lines distinct -> clean coalescing. Group h = l>>4 computes w_h
//   (one exp chain/lane); readlane distributes w_0..3 and the 4 denominators.
// Phase 2: wave w computes output n-tile nt=w of [16 nodes]x[K=4*FIN]@W'[K,64]
//   via KT f16 MFMAs; + bias, leaky 0.1, store.
// MODE 0: layer 1 — x gather dtype per flag; out x2 bf16; ALSO stash the
//   16-node x2 tile in LDS, wave 0 runs the 2-step Bsd2 MFMA -> as2/ad2
//   (fused layer-2 alpha; r20-verified code).
// MODE 1: layer 2 — x2 always bf16; out per flag (bf16 else fp32).

// ---- unique-lane phase 1 for FIN=128 ----
template<bool BF, int STR>
__device__ __forceinline__ void aggr_phase1_u128(const void* __restrict__ xg,
    const float* __restrict__ alpha_s, const float* __restrict__ alpha_d,
    const int* __restrict__ fill, const unsigned short* __restrict__ csr,
    _Float16* __restrict__ ylds, int base, int w, int l)
{
  const int h = l >> 4;                           // own head for exp chain
  #pragma unroll 1
  for (int r = 0; r < 4; ++r){
    const int n = base + w * 4 + r;
    const float adv = alpha_d[n * 4 + h];
    float den = 0.f;
    float acc[4][2];
    #pragma unroll
    for (int hh = 0; hh < 4; ++hh){ acc[hh][0] = 0.f; acc[hh][1] = 0.f; }

    int cnt = fill[n]; if (cnt > CAP) cnt = CAP;
    const unsigned short* cp = csr + ((unsigned)n << 6);
    int p = 0;
    for (; p + 8 <= cnt; p += 8){                 // 8-edge batch
      ushort8 s8 = *(const ushort8*)(cp + p);     // 16B broadcast
      float a[8];
      float lo[8], hi[8];
      #pragma unroll
      for (int i = 0; i < 8; ++i){
        unsigned s = s8[i];
        a[i] = alpha_s[s * 4 + h];
        if (BF){
          unsigned xv = *(const unsigned int*)((const unsigned short*)xg + (size_t)s * 128 + 2 * l);
          lo[i] = bf2f((unsigned short)(xv & 0xFFFFu));
          hi[i] = bf2f((unsigned short)(xv >> 16));
        } else {
          const float* xf = (const float*)xg + (size_t)s * 128 + 2 * l;
          lo[i] = xf[0]; hi[i] = xf[1];
        }
      }
      #pragma unroll
      for (int i = 0; i < 8; ++i){
        float e = a[i] + adv; e = fmaxf(e, 0.2f * e); float wt = __expf(e);
        den += wt;
        float w0 = rdlane(wt, 0),  w1 = rdlane(wt, 16);
        float w2 = rdlane(wt, 32), w3 = rdlane(wt, 48);
        acc[0][0] += w0 * lo[i]; acc[0][1] += w0 * hi[i];
        acc[1][0] += w1 * lo[i]; acc[1][1] += w1 * hi[i];
        acc[2][0] += w2 * lo[i]; acc[2][1] += w2 * hi[i];
        acc[3][0] += w3 * lo[i]; acc[3][1] += w3 * hi[i];
      }
    }
    if (p + 4 <= cnt){                            // 4-edge batch
      ushort4 s4 = *(const ushort4*)(cp + p);
      unsigned ss[4] = {s4.x, s4.y, s4.z, s4.w};
      float a[4], lo[4], hi[4];
      #pragma unroll
      for (int i = 0; i < 4; ++i){
        a[i] = alpha_s[ss[i] * 4 + h];
        if (BF){
          unsigned xv = *(const unsigned int*)((const unsigned short*)xg + (size_t)ss[i] * 128 + 2 * l);
          lo[i] = bf2f((unsigned short)(xv & 0xFFFFu));
          hi[i] = bf2f((unsigned short)(xv >> 16));
        } else {
          const float* xf = (const float*)xg + (size_t)ss[i] * 128 + 2 * l;
          lo[i] = xf[0]; hi[i] = xf[1];
        }
      }
      #pragma unroll
      for (int i = 0; i < 4; ++i){
        float e = a[i] + adv; e = fmaxf(e, 0.2f * e); float wt = __expf(e);
        den += wt;
        float w0 = rdlane(wt, 0),  w1 = rdlane(wt, 16);
        float w2 = rdlane(wt, 32), w3 = rdlane(wt, 48);
        acc[0][0] += w0 * lo[i]; acc[0][1] += w0 * hi[i];
        acc[1][0] += w1 * lo[i]; acc[1][1] += w1 * hi[i];
        acc[2][0] += w2 * lo[i]; acc[2][1] += w2 * hi[i];
        acc[3][0] += w3 * lo[i]; acc[3][1] += w3 * hi[i];
      }
      p += 4;
    }
    for (; p < cnt; ++p){                         // scalar tail (<4)
      unsigned s = cp[p];
      float a = alpha_s[s * 4 + h];
      float lo, hi;
      if (BF){
        unsigned xv = *(const unsigned int*)((const unsigned short*)xg + (size_t)s * 128 + 2 * l);
        lo = bf2f((unsigned short)(xv & 0xFFFFu));
        hi = bf2f((unsigned short)(xv >> 16));
      } else {
        const float* xf = (const float*)xg + (size_t)s * 128 + 2 * l;
        lo = xf[0]; hi = xf[1];
      }
      float e = a + adv; e = fmaxf(e, 0.2f * e); float wt = __expf(e);
      den += wt;
      float w0 = rdlane(wt, 0),  w1 = rdlane(wt, 16);
      float w2 = rdlane(wt, 32), w3 = rdlane(wt, 48);
      acc[0][0] += w0 * lo; acc[0][1] += w0 * hi;
      acc[1][0] += w1 * lo; acc[1][1] += w1 * hi;
      acc[2][0] += w2 * lo; acc[2][1] += w2 * hi;
      acc[3][0] += w3 * lo; acc[3][1] += w3 * hi;
    }
    float d0 = rdlane(den, 0),  d1 = rdlane(den, 16);
    float d2 = rdlane(den, 32), d3 = rdlane(den, 48);
    float rh0 = (d0 > 0.f) ? (1.f / d0) : 0.f;
    float rh1 = (d1 > 0.f) ? (1.f / d1) : 0.f;
    float rh2 = (d2 > 0.f) ? (1.f / d2) : 0.f;
    float rh3 = (d3 > 0.f) ? (1.f / d3) : 0.f;
    const int row = w * 4 + r;
    _Float16* yp = &ylds[row * STR + 2 * l];
    *(f16x2*)(yp +   0) = (f16x2){(_Float16)(acc[0][0] * rh0), (_Float16)(acc[0][1] * rh0)};
    *(f16x2*)(yp + 128) = (f16x2){(_Float16)(acc[1][0] * rh1), (_Float16)(acc[1][1] * rh1)};
    *(f16x2*)(yp + 256) = (f16x2){(_Float16)(acc[2][0] * rh2), (_Float16)(acc[2][1] * rh2)};
    *(f16x2*)(yp + 384) = (f16x2){(_Float16)(acc[3][0] * rh3), (_Float16)(acc[3][1] * rh3)};
  }
}

// ---- unique-lane phase 1 for FIN=64 (x2 always bf16) ----
template<int STR>
__device__ __forceinline__ void aggr_phase1_u64(const unsigned short* __restrict__ xg,
    const float* __restrict__ alpha_s, const float* __restrict__ alpha_d,
    const int* __restrict__ fill, const unsigned short* __restrict__ csr,
    _Float16* __restrict__ ylds, int base, int w, int l)
{
  const int h = l >> 4;                           // own head for exp chain
  #pragma unroll 1
  for (int r = 0; r < 4; ++r){
    const int n = base + w * 4 + r;
    const float adv = alpha_d[n * 4 + h];
    float den = 0.f;
    float acc[4] = {0.f, 0.f, 0.f, 0.f};

    int cnt = fill[n]; if (cnt > CAP) cnt = CAP;
    const unsigned short* cp = csr + ((unsigned)n << 6);
    int p = 0;
    for (; p + 8 <= cnt; p += 8){                 // 8-edge batch
      ushort8 s8 = *(const ushort8*)(cp + p);
      float a[8], xv[8];
      #pragma unroll
      for (int i = 0; i < 8; ++i){
        unsigned s = s8[i];
        a[i] = alpha_s[s * 4 + h];
        xv[i] = bf2f(xg[(size_t)s * 64 + l]);     // 2B unique-lane gather
      }
      #pragma unroll
      for (int i = 0; i < 8; ++i){
        float e = a[i] + adv; e = fmaxf(e, 0.2f * e); float wt = __expf(e);
        den += wt;
        float w0 = rdlane(wt, 0),  w1 = rdlane(wt, 16);
        float w2 = rdlane(wt, 32), w3 = rdlane(wt, 48);
        acc[0] += w0 * xv[i]; acc[1] += w1 * xv[i];
        acc[2] += w2 * xv[i]; acc[3] += w3 * xv[i];
      }
    }
    if (p + 4 <= cnt){                            // 4-edge batch
      ushort4 s4 = *(const ushort4*)(cp + p);
      unsigned ss[4] = {s4.x, s4.y, s4.z, s4.w};
      float a[4], xv[4];
      #pragma unroll
      for (int i = 0; i < 4; ++i){
        a[i] = alpha_s[ss[i] * 4 + h];
        xv[i] = bf2f(xg[(size_t)ss[i] * 64 + l]);
      }
      #pragma unroll
      for (int i = 0; i < 4; ++i){
        float e = a[i] + adv; e = fmaxf(e, 0.2f * e); float wt = __expf(e);
        den += wt;
        float w0 = rdlane(wt, 0),  w1 = rdlane(wt, 16);
        float w2 = rdlane(wt, 32), w3 = rdlane(wt, 48);
        acc[0] += w0 * xv[i]; acc[1] += w1 * xv[i];
        acc[2] += w2 * xv[i]; acc[3] += w3 * xv[i];
      }
      p += 4;
    }
    for (; p < cnt; ++p){                         // scalar tail (<4)
      unsigned s = cp[p];
      float a = alpha_s[s * 4 + h];
      float xv = bf2f(xg[(size_t)s * 64 + l]);
      float e = a + adv; e = fmaxf(e, 0.2f * e); float wt = __expf(e);
      den += wt;
      float w0 = rdlane(wt, 0),  w1 = rdlane(wt, 16);
      float w2 = rdlane(wt, 32), w3 = rdlane(wt, 48);
      acc[0] += w0 * xv; acc[1] += w1 * xv;
      acc[2] += w2 * xv; acc[3] += w3 * xv;
    }
    float d0 = rdlane(den, 0),  d1 = rdlane(den, 16);
    float d2 = rdlane(den, 32), d3 = rdlane(den, 48);
    float rh0 = (d0 > 0.f) ? (1.f / d0) : 0.f;
    float rh1 = (d1 > 0.f) ? (1.f / d1) : 0.f;
    float rh2 = (d2 > 0.f) ? (1.f / d2) : 0.f;
    float rh3 = (d3 > 0.f) ? (1.f / d3) : 0.f;
    const int row = w * 4 + r;
    _Float16* yp = &ylds[row * STR + l];
    yp[0]   = (_Float16)(acc[0] * rh0);
    yp[64]  = (_Float16)(acc[1] * rh1);
    yp[128] = (_Float16)(acc[2] * rh2);
    yp[192] = (_Float16)(acc[3] * rh3);
  }
}

template<int FIN, int MODE>
__global__ __launch_bounds__(256) void k_aggrX(
    const void* __restrict__ xg,                 // [N, FIN] bf16 (or fp32 if MODE 0 && !flag)
    const float* __restrict__ alpha_s, const float* __restrict__ alpha_d,
    const int* __restrict__ fill, const unsigned short* __restrict__ csr,
    const _Float16* __restrict__ Wf,             // f16 B-frags, NT=4, KT=FIN/8
    const float* __restrict__ bias, void* __restrict__ out,
    const int* __restrict__ flag,
    const unsigned short* __restrict__ Bsd2f,    // MODE 0 only
    float* __restrict__ as2, float* __restrict__ ad2)
{
  const int K = 4 * FIN, KT = K / 32, STR = K + 8;
  __shared__ _Float16 ylds[16 * (4 * FIN + 8)];
  __shared__ unsigned short x2t[16 * 72];         // MODE 0: 16-node x2 bf16 tile
  const int tid = threadIdx.x, w = tid >> 6, l = tid & 63;
  const int base = blockIdx.x * 16;               // N divisible by 16

  if (FIN == 128){
    if (MODE == 0 && *flag == 0)
      aggr_phase1_u128<false, STR>(xg, alpha_s, alpha_d, fill, csr, ylds, base, w, l);
    else
      aggr_phase1_u128<true,  STR>(xg, alpha_s, alpha_d, fill, csr, ylds, base, w, l);
  } else {
    aggr_phase1_u64<STR>((const unsigned short*)xg, alpha_s, alpha_d, fill, csr, ylds, base, w, l);
  }
  __syncthreads();

  const int quad = l >> 4, m = l & 15;
  const int nt = w;                               // wave w -> output cols nt*16..
  f32x4 cacc = (f32x4)0.f;
  #pragma unroll
  for (int kt = 0; kt < KT; ++kt){
    f16x8 av = *(const f16x8*)&ylds[m * STR + kt * 32 + quad * 8];
    f16x8 bv = *(const f16x8*)(Wf + ((size_t)(nt * KT + kt) * 64 + l) * 8);
    cacc = __builtin_amdgcn_mfma_f32_16x16x32_f16(av, bv, cacc, 0, 0, 0);
  }
  const int c = nt * 16 + m;
  const float bs = bias[c];
  #pragma unroll
  for (int r2 = 0; r2 < 4; ++r2){
    int node = base + quad * 4 + r2;
    float v = cacc[r2] + bs;
    v = fmaxf(v, 0.1f * v);                       // post-layer leaky 0.1
    if (MODE == 0){
      unsigned short o = f2bf(v);
      ((unsigned short*)out)[(size_t)node * 64 + c] = o;
      x2t[(quad * 4 + r2) * 72 + c] = o;          // stash for fused alpha2
    } else {
      if (*flag) ((unsigned short*)out)[(size_t)node * 64 + c] = f2bf(v);
      else       ((float*)out)[(size_t)node * 64 + c] = v;
    }
  }

  if (MODE == 0){                                 // fused layer-2 alpha (1 wave)
    __syncthreads();
    if (w == 0){
      f32x4 aacc = (f32x4)0.f;
      #pragma unroll
      for (int kt = 0; kt < 2; ++kt){
        short8 af = *(const short8*)&x2t[m * 72 + kt * 32 + quad * 8];
        short8 sd = *(const short8*)(Bsd2f + ((size_t)kt * 64 + l) * 8);
        aacc = __builtin_amdgcn_mfma_f32_16x16x32_bf16(af, sd, aacc, 0, 0, 0);
      }
      if (m < 8){
        float* dstp = (m < 4) ? as2 : ad2;
        int hh = m & 3;
        #pragma unroll
        for (int r = 0; r < 4; ++r){
          int node = base + quad * 4 + r;
          dstp[node * 4 + hh] = aacc[r];
        }
      }
    }
  }
}

// ---------------- launch ----------------

extern "C" void kernel_launch(void* const* d_in, const int* in_sizes, int n_in,
                              void* d_out, int out_size, void* d_ws, size_t ws_size,
                              hipStream_t stream)
{
  const void* x  = d_in[0];
  const int* ei  = (const int*)d_in[1];
  const int* src = ei;
  const int* dst = ei + N_EDGES;

  char* ws = (char*)d_ws;                      // footprint ~16.3 MB
  unsigned short* csr = (unsigned short*)(ws);             // [N*64] ushort padded CSR (6.4 MB)
  unsigned short* x2  = (unsigned short*)(ws + 6400000);   // [N,64] bf16 layer-1 out (6.4 MB)
  float* as_    = (float*)(ws + 12800000);     // [N,4] layer-1 alpha_src
  float* ad_    = (float*)(ws + 13600000);     // [N,4] layer-1 alpha_dst
  float* as2_   = (float*)(ws + 14400000);     // [N,4] layer-2 alpha_src
  float* ad2_   = (float*)(ws + 15200000);     // [N,4] layer-2 alpha_dst
  int*   fill   = (int*)  (ws + 16000000);     // [N] scatter atomics = degree
  _Float16* Wb1f = (_Float16*)(ws + 16200000); // [32768] f16 stacked-W1 frags
  _Float16* Wb2f = (_Float16*)(ws + 16265536); // [16384] f16 stacked-W2 frags
  unsigned short* Bsd1f = (unsigned short*)(ws + 16298304);  // [2048] bf16
  unsigned short* Bsd2f = (unsigned short*)(ws + 16302400);  // [1024] bf16
  float* bc1    = (float*)(ws + 16304448);     // [64]
  float* bc2    = (float*)(ws + 16304704);     // [64]
  int*   flag   = (int*)  (ws + 16304960);     // dtype flag (1 = bf16)

  hipMemsetAsync(fill, 0, N_NODES * sizeof(int), stream);

  SetupPtrs S;
  S.W1 = d_in[2];  S.A1 = d_in[3];  S.aS1 = d_in[4];  S.aD1 = d_in[5];  S.b1 = d_in[6];
  S.W2 = d_in[7];  S.A2 = d_in[8];  S.aS2 = d_in[9];  S.aD2 = d_in[10]; S.b2 = d_in[11];
  S.x  = x;
  k_setup<<<205, 256, 0, stream>>>(S, Wb1f, Wb2f, Bsd1f, Bsd2f, bc1, bc2, flag);

  // scatter (782 blocks, 4 edges/thread) || layer-1 alpha (782 blocks)
  k_scatter_nodeA1<<<NB_SC4 + NB_NODE1, 256, 0, stream>>>(
      src, dst, fill, csr, x, Bsd1f, as_, ad_, flag);

  // layer 1: aggregation + stacked-W1 MFMA -> x2 bf16; + fused layer-2 alphas
  k_aggrX<128, 0><<<N_NODES / 16, 256, 0, stream>>>(
      x, as_, ad_, fill, csr, Wb1f, bc1, x2, flag, Bsd2f, as2_, ad2_);

  // layer 2: aggregation + stacked-W2 MFMA -> final out
  k_aggrX<64, 1><<<N_NODES / 16, 256, 0, stream>>>(
      x2, as2_, ad2_, fill, csr, Wb2f, bc2, d_out, flag, Bsd2f, as2_, ad2_);
}

// Round 12
// 273.862 us; speedup vs baseline: 1.2363x; 1.0117x over previous
//
#include <hip/hip_runtime.h>

// GAT 2-layer fused pipeline for MI355X.
// N=50000 nodes, E=800000 edges, H=4 heads, C=64 channels, D=4 att dims.
// Inputs bf16 (runtime-detected, fp32 fallback); edge_index int32.
//
// Round-26 = r25 resubmit (harness-level Trio failure, no counters; kernel
// re-audited — no race/fault candidates; same signature as r16's infra
// failure which passed unchanged on resubmit).
// r25 = r24 (277.1 us) + two additive changes:
//   (a) fill-zeroing folded into k_setup (52480 threads >= 50000 ints);
//       hipMemsetAsync launch slot removed. 5 -> 4 dispatches.
//   (b) aggr64 phase 1 gains a 16-edge batch tier (2x line-level MLP at the
//       worst 128B gather granule; P(deg>=16) ~ 54%). Consume order identical
//       to two 8-batches -> bitwise-identical output, absmax 1.2207e-4.
//   Scatter (atomic-throughput floor) and aggr128 (fill-path bound) untouched.

#define N_NODES 50000
#define N_EDGES 800000
#define CAP 64        // padded-CSR per-node capacity (max degree ~40 here)
#define NB_SC4 782    // ceil(N_EDGES/1024) scatter blocks (4 edges/thread)
#define NB_NODE1 782  // ceil(N_NODES/64) nodeA blocks

typedef __attribute__((ext_vector_type(8))) short short8;       // 8 bf16
typedef __attribute__((ext_vector_type(8))) _Float16 f16x8;     // 8 fp16
typedef __attribute__((ext_vector_type(2))) _Float16 f16x2;
typedef __attribute__((ext_vector_type(4))) float f32x4;
typedef __attribute__((ext_vector_type(8))) unsigned short ushort8;
typedef __attribute__((ext_vector_type(4))) unsigned short us4v;

__device__ __forceinline__ float bf2f(unsigned short u){
  return __uint_as_float(((unsigned int)u) << 16);
}
__device__ __forceinline__ unsigned short f2bf(float f){
  unsigned int u = __float_as_uint(f);
  u = (u + 0x7FFFu + ((u >> 16) & 1u)) >> 16;   // round-to-nearest-even
  return (unsigned short)u;
}
__device__ __forceinline__ float ldf(const void* p, int i, bool bf){
  return bf ? bf2f(((const unsigned short*)p)[i]) : ((const float*)p)[i];
}
__device__ __forceinline__ float rdlane(float v, int lane){
  return __uint_as_float(__builtin_amdgcn_readlane(__float_as_uint(v), lane));
}

// ---------------- weight prep (205 blocks) + dtype flag + fill zeroing ----------------
// Blocks 0..127: W1' stacked-f16 frags; 128..191: W2'; 192..199: Bsd1 (bf16);
// 200..203: Bsd2; 204: bias copies + flag. All blocks: zero one fill int.
// Stacked weight: W'[q, c] = 0.25*W[f, h*64+c], q = h*Fin+f  (head-mean folded).
// B-frag layout (mfma 16x16x32): Wf[((nt*KT+kt)*64+lane)*8+j] =
//   W'[q = kt*32+(lane>>4)*8+j][c = nt*16+(lane&15)], NT=4.
struct SetupPtrs {
  const void *W1, *A1, *aS1, *aD1, *b1, *W2, *A2, *aS2, *aD2, *b2, *x;
};

__global__ __launch_bounds__(256) void k_setup(SetupPtrs S,
    _Float16* __restrict__ Wb1f, _Float16* __restrict__ Wb2f,
    unsigned short* __restrict__ Bsd1f, unsigned short* __restrict__ Bsd2f,
    float* __restrict__ bc1, float* __restrict__ bc2,
    int* __restrict__ flag, int* __restrict__ fill)
{
  __shared__ int sbf;
  const int tid = threadIdx.x;
  const int bw = blockIdx.x;
  {                                               // fill zeroing (replaces memset)
    int gid = bw * 256 + tid;
    if (gid < N_NODES) fill[gid] = 0;
  }
  if (tid < 64){                                  // wave 0: dtype probe
    unsigned int w = ((const unsigned int*)S.x)[tid] & 0xFFFFu;
    unsigned int e = (w >> 7) & 0xFFu;
    bool hit = (e >= 100u && e <= 135u);
    unsigned long long m = __ballot(hit);
    if (tid == 0) sbf = (__popcll(m) > 40) ? 1 : 0;
  }
  __syncthreads();
  const bool bf = (sbf != 0);
  if (bw < 128){                                  // W1' (K=512, KT=16): 32768 elems
    int t = bw * 256 + tid;
    int j = t & 7, lane = (t >> 3) & 63, kt = (t >> 9) & 15, nt = t >> 13;
    int q = kt * 32 + (lane >> 4) * 8 + j;        // 0..511
    int c = nt * 16 + (lane & 15);
    int h = q >> 7, f = q & 127;
    Wb1f[t] = (_Float16)(0.25f * ldf(S.W1, f * 256 + h * 64 + c, bf));
  } else if (bw < 192){                           // W2' (K=256, KT=8): 16384 elems
    int t = (bw - 128) * 256 + tid;
    int j = t & 7, lane = (t >> 3) & 63, kt = (t >> 9) & 7, nt = t >> 12;
    int q = kt * 32 + (lane >> 4) * 8 + j;        // 0..255
    int c = nt * 16 + (lane & 15);
    int h = q >> 6, f = q & 63;
    Wb2f[t] = (_Float16)(0.25f * ldf(S.W2, f * 256 + h * 64 + c, bf));
  } else if (bw < 200){                           // Bsd1 fragments: 2048 elems (kt<4)
    int t = (bw - 192) * 256 + tid;
    int j = t & 7, lane = (t >> 3) & 63, kt = t >> 9;
    int k = kt * 32 + (lane >> 4) * 8 + j;
    int c = lane & 15;
    float v = 0.f;
    if (c < 4){
      for (int dd = 0; dd < 4; ++dd)
        v += ldf(S.A1, k * 16 + c * 4 + dd, bf) * ldf(S.aS1, c * 4 + dd, bf);
    } else if (c < 8){
      int h = c - 4;
      for (int dd = 0; dd < 4; ++dd)
        v += ldf(S.A1, k * 16 + h * 4 + dd, bf) * ldf(S.aD1, h * 4 + dd, bf);
    }
    Bsd1f[t] = f2bf(v);
  } else if (bw < 204){                           // Bsd2 fragments: 1024 elems (kt<2)
    int t = (bw - 200) * 256 + tid;
    int j = t & 7, lane = (t >> 3) & 63, kt = t >> 9;
    int k = kt * 32 + (lane >> 4) * 8 + j;
    int c = lane & 15;
    float v = 0.f;
    if (c < 4){
      for (int dd = 0; dd < 4; ++dd)
        v += ldf(S.A2, k * 16 + c * 4 + dd, bf) * ldf(S.aS2, c * 4 + dd, bf);
    } else if (c < 8){
      int h = c - 4;
      for (int dd = 0; dd < 4; ++dd)
        v += ldf(S.A2, k * 16 + h * 4 + dd, bf) * ldf(S.aD2, h * 4 + dd, bf);
    }
    Bsd2f[t] = f2bf(v);
  } else {                                        // bias copies + flag
    if (tid < 64)       bc1[tid] = ldf(S.b1, tid, bf);
    else if (tid < 128) bc2[tid - 64] = ldf(S.b2, tid - 64, bf);
    else if (tid == 128) *flag = bf ? 1 : 0;
  }
}

// ---------------- layer-1 alpha transform ----------------

__device__ __forceinline__ void nodeA_body(int nblk, int tid,
    const void* __restrict__ xin_, const unsigned short* __restrict__ Bsdf,
    float* __restrict__ alpha_s, float* __restrict__ alpha_d,
    const int* __restrict__ flag)
{
  const int F = 128, STR = F + 8, KT = 4, CH = F / 8;
  __shared__ unsigned short xs[64 * 136];
  const int base = nblk * 64;
  const bool bf = (*flag != 0);
  for (int v = tid; v < 64 * CH; v += 256){
    int row = v / CH, c8 = v % CH;
    int node = base + row; if (node >= N_NODES) node = N_NODES - 1;
    size_t g = (size_t)node * F + c8 * 8;
    ushort8 u;
    if (bf){
      u = *(const ushort8*)((const unsigned short*)xin_ + g);
    } else {
      const float* xf = (const float*)xin_ + g;
      float4 f0 = *(const float4*)xf, f1 = *(const float4*)(xf + 4);
      u[0]=f2bf(f0.x); u[1]=f2bf(f0.y); u[2]=f2bf(f0.z); u[3]=f2bf(f0.w);
      u[4]=f2bf(f1.x); u[5]=f2bf(f1.y); u[6]=f2bf(f1.z); u[7]=f2bf(f1.w);
    }
    *(ushort8*)&xs[row * STR + c8 * 8] = u;
  }
  __syncthreads();

  const int wave = tid >> 6, l = tid & 63;
  const int quad = l >> 4, m = l & 15;
  const int wbase = base + wave * 16;

  f32x4 aacc = (f32x4)0.f;
  #pragma unroll
  for (int kt = 0; kt < KT; ++kt){
    short8 af = *(const short8*)&xs[(wave * 16 + m) * STR + kt * 32 + quad * 8];
    short8 sdfrag = *(const short8*)(Bsdf + ((size_t)kt * 64 + l) * 8);
    aacc = __builtin_amdgcn_mfma_f32_16x16x32_bf16(af, sdfrag, aacc, 0, 0, 0);
  }
  if (m < 8){
    float* dstp = (m < 4) ? alpha_s : alpha_d;
    int hh = m & 3;
    #pragma unroll
    for (int r = 0; r < 4; ++r){
      int node = wbase + quad * 4 + r;
      if (node < N_NODES) dstp[node * 4 + hh] = aacc[r];
    }
  }
}

// ---------------- fused padded-CSR scatter (ushort, 4-edge ILP) + layer-1 alpha ----------------

__global__ __launch_bounds__(256) void k_scatter_nodeA1(
    const int* __restrict__ src, const int* __restrict__ dst,
    int* __restrict__ fill, unsigned short* __restrict__ csr,
    const void* __restrict__ xin_, const unsigned short* __restrict__ Bsdf,
    float* __restrict__ alpha_s, float* __restrict__ alpha_d,
    const int* __restrict__ flag)
{
  const int b = blockIdx.x, tid = threadIdx.x;
  if (b < NB_SC4){
    const int ebase = b * 1024 + tid;
    int d[4], s[4];
    #pragma unroll
    for (int i = 0; i < 4; ++i){
      int e = ebase + i * 256;
      bool ok = (e < N_EDGES);
      d[i] = ok ? dst[e] : -1;
      s[i] = ok ? src[e] : 0;
    }
    #pragma unroll
    for (int i = 0; i < 4; ++i){
      if (d[i] >= 0){
        int r = atomicAdd(&fill[d[i]], 1);
        if (r < CAP) csr[((unsigned)d[i] << 6) + r] = (unsigned short)s[i];
      }
    }
    return;
  }
  nodeA_body(b - NB_SC4, tid, xin_, Bsdf, alpha_s, alpha_d, flag);
}

// ---------------- weighted-feature aggregation + stacked-W MFMA epilogue ----------------
// Block = 256 thr = 4 waves, 16 dst nodes (wave w owns nodes base+4w..base+4w+3).
//
// Phase 1 (unique-lane, both layers): FIN=128: lane l owns features {2l,2l+1}
//   (4B dword/edge); FIN=64: lane l owns feature l (2B ushort/edge). All 64
//   lanes' lines distinct -> clean coalescing. Group h = l>>4 computes w_h
//   (one exp chain/lane); readlane distributes w_0..3 and the 4 denominators.
//   FIN=64 adds a 16-edge batch tier (r25) for 2x line-level MLP.
// Phase 2: wave w computes output n-tile nt=w of [16 nodes]x[K=4*FIN]@W'[K,64]
//   via KT f16 MFMAs; + bias, leaky 0.1, store.
// MODE 0: layer 1 — x gather dtype per flag; out x2 bf16; ALSO stash the
//   16-node x2 tile in LDS, wave 0 runs the 2-step Bsd2 MFMA -> as2/ad2.
// MODE 1: layer 2 — x2 always bf16; out per flag (bf16 else fp32).

// ---- unique-lane phase 1 for FIN=128 ----
template<bool BF, int STR>
__device__ __forceinline__ void aggr_phase1_u128(const void* __restrict__ xg,
    const float* __restrict__ alpha_s, const float* __restrict__ alpha_d,
    const int* __restrict__ fill, const unsigned short* __restrict__ csr,
    _Float16* __restrict__ ylds, int base, int w, int l)
{
  const int h = l >> 4;                           // own head for exp chain
  #pragma unroll 1
  for (int r = 0; r < 4; ++r){
    const int n = base + w * 4 + r;
    const float adv = alpha_d[n * 4 + h];
    float den = 0.f;
    float acc[4][2];
    #pragma unroll
    for (int hh = 0; hh < 4; ++hh){ acc[hh][0] = 0.f; acc[hh][1] = 0.f; }

    int cnt = fill[n]; if (cnt > CAP) cnt = CAP;
    const unsigned short* cp = csr + ((unsigned)n << 6);
    int p = 0;
    for (; p + 8 <= cnt; p += 8){                 // 8-edge batch
      ushort8 s8 = *(const ushort8*)(cp + p);     // 16B broadcast
      float a[8];
      float lo[8], hi[8];
      #pragma unroll
      for (int i = 0; i < 8; ++i){
        unsigned s = s8[i];
        a[i] = alpha_s[s * 4 + h];
        if (BF){
          unsigned xv = *(const unsigned int*)((const unsigned short*)xg + (size_t)s * 128 + 2 * l);
          lo[i] = bf2f((unsigned short)(xv & 0xFFFFu));
          hi[i] = bf2f((unsigned short)(xv >> 16));
        } else {
          const float* xf = (const float*)xg + (size_t)s * 128 + 2 * l;
          lo[i] = xf[0]; hi[i] = xf[1];
        }
      }
      #pragma unroll
      for (int i = 0; i < 8; ++i){
        float e = a[i] + adv; e = fmaxf(e, 0.2f * e); float wt = __expf(e);
        den += wt;
        float w0 = rdlane(wt, 0),  w1 = rdlane(wt, 16);
        float w2 = rdlane(wt, 32), w3 = rdlane(wt, 48);
        acc[0][0] += w0 * lo[i]; acc[0][1] += w0 * hi[i];
        acc[1][0] += w1 * lo[i]; acc[1][1] += w1 * hi[i];
        acc[2][0] += w2 * lo[i]; acc[2][1] += w2 * hi[i];
        acc[3][0] += w3 * lo[i]; acc[3][1] += w3 * hi[i];
      }
    }
    if (p + 4 <= cnt){                            // 4-edge batch
      ushort4 s4 = *(const ushort4*)(cp + p);
      unsigned ss[4] = {s4.x, s4.y, s4.z, s4.w};
      float a[4], lo[4], hi[4];
      #pragma unroll
      for (int i = 0; i < 4; ++i){
        a[i] = alpha_s[ss[i] * 4 + h];
        if (BF){
          unsigned xv = *(const unsigned int*)((const unsigned short*)xg + (size_t)ss[i] * 128 + 2 * l);
          lo[i] = bf2f((unsigned short)(xv & 0xFFFFu));
          hi[i] = bf2f((unsigned short)(xv >> 16));
        } else {
          const float* xf = (const float*)xg + (size_t)ss[i] * 128 + 2 * l;
          lo[i] = xf[0]; hi[i] = xf[1];
        }
      }
      #pragma unroll
      for (int i = 0; i < 4; ++i){
        float e = a[i] + adv; e = fmaxf(e, 0.2f * e); float wt = __expf(e);
        den += wt;
        float w0 = rdlane(wt, 0),  w1 = rdlane(wt, 16);
        float w2 = rdlane(wt, 32), w3 = rdlane(wt, 48);
        acc[0][0] += w0 * lo[i]; acc[0][1] += w0 * hi[i];
        acc[1][0] += w1 * lo[i]; acc[1][1] += w1 * hi[i];
        acc[2][0] += w2 * lo[i]; acc[2][1] += w2 * hi[i];
        acc[3][0] += w3 * lo[i]; acc[3][1] += w3 * hi[i];
      }
      p += 4;
    }
    for (; p < cnt; ++p){                         // scalar tail (<4)
      unsigned s = cp[p];
      float a = alpha_s[s * 4 + h];
      float lo, hi;
      if (BF){
        unsigned xv = *(const unsigned int*)((const unsigned short*)xg + (size_t)s * 128 + 2 * l);
        lo = bf2f((unsigned short)(xv & 0xFFFFu));
        hi = bf2f((unsigned short)(xv >> 16));
      } else {
        const float* xf = (const float*)xg + (size_t)s * 128 + 2 * l;
        lo = xf[0]; hi = xf[1];
      }
      float e = a + adv; e = fmaxf(e, 0.2f * e); float wt = __expf(e);
      den += wt;
      float w0 = rdlane(wt, 0),  w1 = rdlane(wt, 16);
      float w2 = rdlane(wt, 32), w3 = rdlane(wt, 48);
      acc[0][0] += w0 * lo; acc[0][1] += w0 * hi;
      acc[1][0] += w1 * lo; acc[1][1] += w1 * hi;
      acc[2][0] += w2 * lo; acc[2][1] += w2 * hi;
      acc[3][0] += w3 * lo; acc[3][1] += w3 * hi;
    }
    float d0 = rdlane(den, 0),  d1 = rdlane(den, 16);
    float d2 = rdlane(den, 32), d3 = rdlane(den, 48);
    float rh0 = (d0 > 0.f) ? (1.f / d0) : 0.f;
    float rh1 = (d1 > 0.f) ? (1.f / d1) : 0.f;
    float rh2 = (d2 > 0.f) ? (1.f / d2) : 0.f;
    float rh3 = (d3 > 0.f) ? (1.f / d3) : 0.f;
    const int row = w * 4 + r;
    _Float16* yp = &ylds[row * STR + 2 * l];
    *(f16x2*)(yp +   0) = (f16x2){(_Float16)(acc[0][0] * rh0), (_Float16)(acc[0][1] * rh0)};
    *(f16x2*)(yp + 128) = (f16x2){(_Float16)(acc[1][0] * rh1), (_Float16)(acc[1][1] * rh1)};
    *(f16x2*)(yp + 256) = (f16x2){(_Float16)(acc[2][0] * rh2), (_Float16)(acc[2][1] * rh2)};
    *(f16x2*)(yp + 384) = (f16x2){(_Float16)(acc[3][0] * rh3), (_Float16)(acc[3][1] * rh3)};
  }
}

// ---- unique-lane phase 1 for FIN=64 (x2 always bf16), 16-edge batches ----
template<int STR>
__device__ __forceinline__ void aggr_phase1_u64(const unsigned short* __restrict__ xg,
    const float* __restrict__ alpha_s, const float* __restrict__ alpha_d,
    const int* __restrict__ fill, const unsigned short* __restrict__ csr,
    _Float16* __restrict__ ylds, int base, int w, int l)
{
  const int h = l >> 4;                           // own head for exp chain
  #pragma unroll 1
  for (int r = 0; r < 4; ++r){
    const int n = base + w * 4 + r;
    const float adv = alpha_d[n * 4 + h];
    float den = 0.f;
    float acc[4] = {0.f, 0.f, 0.f, 0.f};

    int cnt = fill[n]; if (cnt > CAP) cnt = CAP;
    const unsigned short* cp = csr + ((unsigned)n << 6);
    int p = 0;
    for (; p + 16 <= cnt; p += 16){               // 16-edge batch (2x MLP)
      ushort8 sa = *(const ushort8*)(cp + p);
      ushort8 sb = *(const ushort8*)(cp + p + 8);
      float a[16], xv[16];
      #pragma unroll
      for (int i = 0; i < 8; ++i){
        unsigned s0 = sa[i], s1 = sb[i];
        a[i]     = alpha_s[s0 * 4 + h];
        a[i + 8] = alpha_s[s1 * 4 + h];
        xv[i]     = bf2f(xg[(size_t)s0 * 64 + l]);
        xv[i + 8] = bf2f(xg[(size_t)s1 * 64 + l]);
      }
      #pragma unroll
      for (int i = 0; i < 16; ++i){
        float e = a[i] + adv; e = fmaxf(e, 0.2f * e); float wt = __expf(e);
        den += wt;
        float w0 = rdlane(wt, 0),  w1 = rdlane(wt, 16);
        float w2 = rdlane(wt, 32), w3 = rdlane(wt, 48);
        acc[0] += w0 * xv[i]; acc[1] += w1 * xv[i];
        acc[2] += w2 * xv[i]; acc[3] += w3 * xv[i];
      }
    }
    if (p + 8 <= cnt){                            // 8-edge batch
      ushort8 s8 = *(const ushort8*)(cp + p);
      float a[8], xv[8];
      #pragma unroll
      for (int i = 0; i < 8; ++i){
        unsigned s = s8[i];
        a[i] = alpha_s[s * 4 + h];
        xv[i] = bf2f(xg[(size_t)s * 64 + l]);
      }
      #pragma unroll
      for (int i = 0; i < 8; ++i){
        float e = a[i] + adv; e = fmaxf(e, 0.2f * e); float wt = __expf(e);
        den += wt;
        float w0 = rdlane(wt, 0),  w1 = rdlane(wt, 16);
        float w2 = rdlane(wt, 32), w3 = rdlane(wt, 48);
        acc[0] += w0 * xv[i]; acc[1] += w1 * xv[i];
        acc[2] += w2 * xv[i]; acc[3] += w3 * xv[i];
      }
      p += 8;
    }
    if (p + 4 <= cnt){                            // 4-edge batch
      ushort4 s4 = *(const ushort4*)(cp + p);
      unsigned ss[4] = {s4.x, s4.y, s4.z, s4.w};
      float a[4], xv[4];
      #pragma unroll
      for (int i = 0; i < 4; ++i){
        a[i] = alpha_s[ss[i] * 4 + h];
        xv[i] = bf2f(xg[(size_t)ss[i] * 64 + l]);
      }
      #pragma unroll
      for (int i = 0; i < 4; ++i){
        float e = a[i] + adv; e = fmaxf(e, 0.2f * e); float wt = __expf(e);
        den += wt;
        float w0 = rdlane(wt, 0),  w1 = rdlane(wt, 16);
        float w2 = rdlane(wt, 32), w3 = rdlane(wt, 48);
        acc[0] += w0 * xv[i]; acc[1] += w1 * xv[i];
        acc[2] += w2 * xv[i]; acc[3] += w3 * xv[i];
      }
      p += 4;
    }
    for (; p < cnt; ++p){                         // scalar tail (<4)
      unsigned s = cp[p];
      float a = alpha_s[s * 4 + h];
      float xv = bf2f(xg[(size_t)s * 64 + l]);
      float e = a + adv; e = fmaxf(e, 0.2f * e); float wt = __expf(e);
      den += wt;
      float w0 = rdlane(wt, 0),  w1 = rdlane(wt, 16);
      float w2 = rdlane(wt, 32), w3 = rdlane(wt, 48);
      acc[0] += w0 * xv; acc[1] += w1 * xv;
      acc[2] += w2 * xv; acc[3] += w3 * xv;
    }
    float d0 = rdlane(den, 0),  d1 = rdlane(den, 16);
    float d2 = rdlane(den, 32), d3 = rdlane(den, 48);
    float rh0 = (d0 > 0.f) ? (1.f / d0) : 0.f;
    float rh1 = (d1 > 0.f) ? (1.f / d1) : 0.f;
    float rh2 = (d2 > 0.f) ? (1.f / d2) : 0.f;
    float rh3 = (d3 > 0.f) ? (1.f / d3) : 0.f;
    const int row = w * 4 + r;
    _Float16* yp = &ylds[row * STR + l];
    yp[0]   = (_Float16)(acc[0] * rh0);
    yp[64]  = (_Float16)(acc[1] * rh1);
    yp[128] = (_Float16)(acc[2] * rh2);
    yp[192] = (_Float16)(acc[3] * rh3);
  }
}

template<int FIN, int MODE>
__global__ __launch_bounds__(256) void k_aggrX(
    const void* __restrict__ xg,                 // [N, FIN] bf16 (or fp32 if MODE 0 && !flag)
    const float* __restrict__ alpha_s, const float* __restrict__ alpha_d,
    const int* __restrict__ fill, const unsigned short* __restrict__ csr,
    const _Float16* __restrict__ Wf,             // f16 B-frags, NT=4, KT=FIN/8
    const float* __restrict__ bias, void* __restrict__ out,
    const int* __restrict__ flag,
    const unsigned short* __restrict__ Bsd2f,    // MODE 0 only
    float* __restrict__ as2, float* __restrict__ ad2)
{
  const int K = 4 * FIN, KT = K / 32, STR = K + 8;
  __shared__ _Float16 ylds[16 * (4 * FIN + 8)];
  __shared__ unsigned short x2t[16 * 72];         // MODE 0: 16-node x2 bf16 tile
  const int tid = threadIdx.x, w = tid >> 6, l = tid & 63;
  const int base = blockIdx.x * 16;               // N divisible by 16

  if (FIN == 128){
    if (MODE == 0 && *flag == 0)
      aggr_phase1_u128<false, STR>(xg, alpha_s, alpha_d, fill, csr, ylds, base, w, l);
    else
      aggr_phase1_u128<true,  STR>(xg, alpha_s, alpha_d, fill, csr, ylds, base, w, l);
  } else {
    aggr_phase1_u64<STR>((const unsigned short*)xg, alpha_s, alpha_d, fill, csr, ylds, base, w, l);
  }
  __syncthreads();

  const int quad = l >> 4, m = l & 15;
  const int nt = w;                               // wave w -> output cols nt*16..
  f32x4 cacc = (f32x4)0.f;
  #pragma unroll
  for (int kt = 0; kt < KT; ++kt){
    f16x8 av = *(const f16x8*)&ylds[m * STR + kt * 32 + quad * 8];
    f16x8 bv = *(const f16x8*)(Wf + ((size_t)(nt * KT + kt) * 64 + l) * 8);
    cacc = __builtin_amdgcn_mfma_f32_16x16x32_f16(av, bv, cacc, 0, 0, 0);
  }
  const int c = nt * 16 + m;
  const float bs = bias[c];
  #pragma unroll
  for (int r2 = 0; r2 < 4; ++r2){
    int node = base + quad * 4 + r2;
    float v = cacc[r2] + bs;
    v = fmaxf(v, 0.1f * v);                       // post-layer leaky 0.1
    if (MODE == 0){
      unsigned short o = f2bf(v);
      ((unsigned short*)out)[(size_t)node * 64 + c] = o;
      x2t[(quad * 4 + r2) * 72 + c] = o;          // stash for fused alpha2
    } else {
      if (*flag) ((unsigned short*)out)[(size_t)node * 64 + c] = f2bf(v);
      else       ((float*)out)[(size_t)node * 64 + c] = v;
    }
  }

  if (MODE == 0){                                 // fused layer-2 alpha (1 wave)
    __syncthreads();
    if (w == 0){
      f32x4 aacc = (f32x4)0.f;
      #pragma unroll
      for (int kt = 0; kt < 2; ++kt){
        short8 af = *(const short8*)&x2t[m * 72 + kt * 32 + quad * 8];
        short8 sd = *(const short8*)(Bsd2f + ((size_t)kt * 64 + l) * 8);
        aacc = __builtin_amdgcn_mfma_f32_16x16x32_bf16(af, sd, aacc, 0, 0, 0);
      }
      if (m < 8){
        float* dstp = (m < 4) ? as2 : ad2;
        int hh = m & 3;
        #pragma unroll
        for (int r = 0; r < 4; ++r){
          int node = base + quad * 4 + r;
          dstp[node * 4 + hh] = aacc[r];
        }
      }
    }
  }
}

// ---------------- launch ----------------

extern "C" void kernel_launch(void* const* d_in, const int* in_sizes, int n_in,
                              void* d_out, int out_size, void* d_ws, size_t ws_size,
                              hipStream_t stream)
{
  const void* x  = d_in[0];
  const int* ei  = (const int*)d_in[1];
  const int* src = ei;
  const int* dst = ei + N_EDGES;

  char* ws = (char*)d_ws;                      // footprint ~16.3 MB
  unsigned short* csr = (unsigned short*)(ws);             // [N*64] ushort padded CSR (6.4 MB)
  unsigned short* x2  = (unsigned short*)(ws + 6400000);   // [N,64] bf16 layer-1 out (6.4 MB)
  float* as_    = (float*)(ws + 12800000);     // [N,4] layer-1 alpha_src
  float* ad_    = (float*)(ws + 13600000);     // [N,4] layer-1 alpha_dst
  float* as2_   = (float*)(ws + 14400000);     // [N,4] layer-2 alpha_src
  float* ad2_   = (float*)(ws + 15200000);     // [N,4] layer-2 alpha_dst
  int*   fill   = (int*)  (ws + 16000000);     // [N] scatter atomics = degree
  _Float16* Wb1f = (_Float16*)(ws + 16200000); // [32768] f16 stacked-W1 frags
  _Float16* Wb2f = (_Float16*)(ws + 16265536); // [16384] f16 stacked-W2 frags
  unsigned short* Bsd1f = (unsigned short*)(ws + 16298304);  // [2048] bf16
  unsigned short* Bsd2f = (unsigned short*)(ws + 16302400);  // [1024] bf16
  float* bc1    = (float*)(ws + 16304448);     // [64]
  float* bc2    = (float*)(ws + 16304704);     // [64]
  int*   flag   = (int*)  (ws + 16304960);     // dtype flag (1 = bf16)

  SetupPtrs S;
  S.W1 = d_in[2];  S.A1 = d_in[3];  S.aS1 = d_in[4];  S.aD1 = d_in[5];  S.b1 = d_in[6];
  S.W2 = d_in[7];  S.A2 = d_in[8];  S.aS2 = d_in[9];  S.aD2 = d_in[10]; S.b2 = d_in[11];
  S.x  = x;
  // weight prep + dtype flag + fill zeroing (memset slot removed)
  k_setup<<<205, 256, 0, stream>>>(S, Wb1f, Wb2f, Bsd1f, Bsd2f, bc1, bc2, flag, fill);

  // scatter (782 blocks, 4 edges/thread) || layer-1 alpha (782 blocks)
  k_scatter_nodeA1<<<NB_SC4 + NB_NODE1, 256, 0, stream>>>(
      src, dst, fill, csr, x, Bsd1f, as_, ad_, flag);

  // layer 1: aggregation + stacked-W1 MFMA -> x2 bf16; + fused layer-2 alphas
  k_aggrX<128, 0><<<N_NODES / 16, 256, 0, stream>>>(
      x, as_, ad_, fill, csr, Wb1f, bc1, x2, flag, Bsd2f, as2_, ad2_);

  // layer 2: aggregation + stacked-W2 MFMA -> final out
  k_aggrX<64, 1><<<N_NODES / 16, 256, 0, stream>>>(
      x2, as2_, ad2_, fill, csr, Wb2f, bc2, d_out, flag, Bsd2f, as2_, ad2_);
}